// Round 4
// baseline (504.960 us; speedup 1.0000x reference)
//
#include <hip/hip_runtime.h>
#include <math.h>

// Problem constants
constexpr int Bc  = 4;
constexpr int Sc  = 2048;
constexpr int Dc  = 512;
constexpr int Hc  = 8;
constexpr int DKc = 64;
constexpr int Mc  = Bc * Sc;   // 8192 rows

constexpr float SCALE_Q = 0.180336880111120426f;   // (1/8) * log2(e): /H quirk + exp2 base

typedef __attribute__((ext_vector_type(8)))  short s16x8;   // 8 bf16 MFMA frag
typedef __attribute__((ext_vector_type(4)))  float f32x4;   // 16x16 accumulator
typedef __attribute__((ext_vector_type(16))) float f32x16;  // 32x32 accumulator

__device__ __forceinline__ unsigned short f2bf(float f) {
    __bf16 h = (__bf16)f;                 // RNE convert
    return __builtin_bit_cast(unsigned short, h);
}

__device__ __forceinline__ float fexp2(float x) {
#if __has_builtin(__builtin_amdgcn_exp2f)
    return __builtin_amdgcn_exp2f(x);
#else
    return __expf(x * 0.6931471805599453f);
#endif
}

// ---------------------------------------------------------------------------
// mask [B,1,S,S] int32 -> keep-bit words: bit j of word w == (mask[w*64+j]!=0)
// ---------------------------------------------------------------------------
__global__ __launch_bounds__(256)
void pack_mask(const int* __restrict__ mask, unsigned long long* __restrict__ out,
               int nwords)
{
    int gw   = (blockIdx.x * blockDim.x + threadIdx.x) >> 6;
    int lane = threadIdx.x & 63;
    int nw   = (gridDim.x * blockDim.x) >> 6;
    for (int w = gw; w < nwords; w += nw) {
        int v = mask[(size_t)w * 64 + lane];
        unsigned long long bits = __ballot(v != 0);
        if (lane == 0) out[w] = bits;
    }
}

// ---------------------------------------------------------------------------
// fp32 -> bf16 elementwise, up to 4 tensors (blockIdx.y selects), n4 float4s each
// ---------------------------------------------------------------------------
__global__ __launch_bounds__(256)
void cvt4(const float* __restrict__ i0, const float* __restrict__ i1,
          const float* __restrict__ i2, const float* __restrict__ i3,
          unsigned short* __restrict__ o0, unsigned short* __restrict__ o1,
          unsigned short* __restrict__ o2, unsigned short* __restrict__ o3,
          int n4)
{
    const float* in; unsigned short* out;
    switch (blockIdx.y) {
        case 0: in = i0; out = o0; break;
        case 1: in = i1; out = o1; break;
        case 2: in = i2; out = o2; break;
        default: in = i3; out = o3; break;
    }
    int i = blockIdx.x * 256 + threadIdx.x;
    if (i < n4) {
        float4 v = ((const float4*)in)[i];
        ushort4 r;
        r.x = f2bf(v.x); r.y = f2bf(v.y); r.z = f2bf(v.z); r.w = f2bf(v.w);
        ((ushort4*)out)[i] = r;
    }
}

// ---------------------------------------------------------------------------
// bf16-MFMA GEMM (all-bf16 inputs): out = (X[M,512] @ W[512,512]^T + bias)*scale
// Tile 128m x 64n, 256 thr = 4 waves (2x2), 16x16x32 MFMA, register-prefetch
// double buffer (next k-tile's loads overlap MFMAs).
// MODE 0: fp32 flat [M,512]
// MODE 1: bf16 head layout   [((b*H+h)*S+s)*64 + dk]      (Q: scale=SCALE_Q, K)
// MODE 2: bf16 head transposed [((b*H+h)*64+dk)*S + swap23(s)]  (V; key-bit
//         swap makes attention's P B-frags lane-local — see attn_mfma)
// ---------------------------------------------------------------------------
template<int MODE>
__global__ __launch_bounds__(256, 2)
void gemm_mfma(const unsigned short* __restrict__ X, const unsigned short* __restrict__ W,
               const float* __restrict__ bias, void* __restrict__ outv, float scale)
{
    __shared__ unsigned short Xs[128][72];
    __shared__ unsigned short Ws[64][72];

    const int tid = threadIdx.x;
    const int w = tid >> 6, lane = tid & 63, ln = lane & 15, qd = lane >> 4;
    const int wm = (w >> 1) * 64, wn = (w & 1) * 32;
    const int row0 = blockIdx.x * 128, col0 = blockIdx.y * 64;

    f32x4 acc[4][2];
#pragma unroll
    for (int mt = 0; mt < 4; ++mt)
#pragma unroll
        for (int nt = 0; nt < 2; ++nt) acc[mt][nt] = f32x4{0.f, 0.f, 0.f, 0.f};

    uint4 xs[4], ws[2];
    auto load = [&](int k0) {
#pragma unroll
        for (int c = 0; c < 4; ++c) {
            int idx = tid + c * 256, r = idx >> 3, cc = idx & 7;
            xs[c] = *(const uint4*)(X + (size_t)(row0 + r) * 512 + k0 + cc * 8);
        }
#pragma unroll
        for (int c = 0; c < 2; ++c) {
            int idx = tid + c * 256, r = idx >> 3, cc = idx & 7;
            ws[c] = *(const uint4*)(W + (size_t)(col0 + r) * 512 + k0 + cc * 8);
        }
    };

    load(0);
    for (int k0 = 0; k0 < 512; k0 += 64) {
        __syncthreads();
#pragma unroll
        for (int c = 0; c < 4; ++c) {
            int idx = tid + c * 256, r = idx >> 3, cc = idx & 7;
            *(uint4*)&Xs[r][cc * 8] = xs[c];
        }
#pragma unroll
        for (int c = 0; c < 2; ++c) {
            int idx = tid + c * 256, r = idx >> 3, cc = idx & 7;
            *(uint4*)&Ws[r][cc * 8] = ws[c];
        }
        __syncthreads();
        if (k0 + 64 < 512) load(k0 + 64);   // prefetch overlaps MFMAs below
#pragma unroll
        for (int kc = 0; kc < 2; ++kc) {
            s16x8 af[4], bfr[2];
#pragma unroll
            for (int mt = 0; mt < 4; ++mt)
                af[mt] = *(const s16x8*)&Xs[wm + mt * 16 + ln][kc * 32 + qd * 8];
#pragma unroll
            for (int nt = 0; nt < 2; ++nt)
                bfr[nt] = *(const s16x8*)&Ws[wn + nt * 16 + ln][kc * 32 + qd * 8];
#pragma unroll
            for (int mt = 0; mt < 4; ++mt)
#pragma unroll
                for (int nt = 0; nt < 2; ++nt)
                    acc[mt][nt] = __builtin_amdgcn_mfma_f32_16x16x32_bf16(
                        af[mt], bfr[nt], acc[mt][nt], 0, 0, 0);
        }
    }

    // epilogue: C layout m = mbase + r, n = col0+wn+nt*16+ln
#pragma unroll
    for (int nt = 0; nt < 2; ++nt) {
        const int n = col0 + wn + nt * 16 + ln;
        const float bz = bias[n];
#pragma unroll
        for (int mt = 0; mt < 4; ++mt) {
            const int mbase = row0 + wm + mt * 16 + qd * 4;
            if (MODE == 0) {
                float* o = (float*)outv;
#pragma unroll
                for (int r = 0; r < 4; ++r)
                    o[(size_t)(mbase + r) * 512 + n] = acc[mt][nt][r] + bz;
            } else if (MODE == 1) {
                unsigned short* o = (unsigned short*)outv;
                const int h = n >> 6, dk = n & 63;
#pragma unroll
                for (int r = 0; r < 4; ++r) {
                    int m = mbase + r, b = m >> 11, s = m & 2047;
                    o[((size_t)(b * Hc + h) * Sc + s) * 64 + dk] =
                        f2bf((acc[mt][nt][r] + bz) * scale);
                }
            } else {
                unsigned short* o = (unsigned short*)outv;
                const int h = n >> 6, dk = n & 63;
                const int b = mbase >> 11, s0 = mbase & 2047;
                const int ss = (s0 & ~12) | ((s0 & 4) << 1) | ((s0 & 8) >> 1); // swap bits 2,3
                ushort4 pk;
                pk.x = f2bf((acc[mt][nt][0] + bz) * scale);
                pk.y = f2bf((acc[mt][nt][1] + bz) * scale);
                pk.z = f2bf((acc[mt][nt][2] + bz) * scale);
                pk.w = f2bf((acc[mt][nt][3] + bz) * scale);
                *(ushort4*)(o + ((size_t)(b * Hc + h) * 64 + dk) * Sc + ss) = pk;
            }
        }
    }
}

// ---------------------------------------------------------------------------
// Split-K bf16 32x32x16-MFMA flash attention, max-free softmax.
// Grid (S/64, B*H), 256 thr = 4 waves = 2 q-groups x 2 key-halves.
// Wave (g,kh): q = q0+32g+ln, keys kh*1024 .. +1024 in 32-key tiles (32 iters).
// Per iter: QK (4 MFMA) -> p=exp2(masked s') (scores bounded |s|<~2: no max
// needed; masked -> exp2(-1e9)=0) -> PV (4 MFMA) with B-frags = own p regs
// (V key axis is bit2<->bit3 swapped at projection store; under that
// permutation C-reg order == B-frag order). Partials combine linearly at end
// (no max state). Register-prefetch K/V tile i+1 during compute of i.
// ---------------------------------------------------------------------------
__global__ __launch_bounds__(256, 4)
void attn_mfma(const unsigned short* __restrict__ qh, const unsigned short* __restrict__ kh,
               const unsigned short* __restrict__ vt, const unsigned* __restrict__ mbits,
               unsigned short* __restrict__ ctx)
{
    __shared__ uint4 smem4[19456 / 16];    // 2 x (Ks 32x72 + Vs 64x40) shorts
    char* smem = (char*)smem4;

    const int bh = blockIdx.y, b = bh >> 3, h = bh & 7;
    const int q0 = blockIdx.x * 64;
    const int tid = threadIdx.x;
    const int w = tid >> 6;
    const int g = w >> 1;            // q-group
    const int kh_ = w & 1;           // key half
    const int lane = tid & 63, ln = lane & 31, hf = lane >> 5;
    const int qrow = q0 + g * 32 + ln;

    unsigned short* Ks = (unsigned short*)(smem + kh_ * 9728);          // [32][72]
    unsigned short* Vs = (unsigned short*)(smem + kh_ * 9728 + 4608);   // [64][40]

    const int st = ((tid >> 7) << 6) | (tid & 63);   // staging id within kh-group, 0..127

    // Q B-frags, resident: Q[qrow][kc*16 + hf*8 + j]
    s16x8 qf[4];
    {
        const unsigned short* qp = qh + ((size_t)bh * Sc + qrow) * 64 + hf * 8;
#pragma unroll
        for (int kc = 0; kc < 4; ++kc) qf[kc] = *(const s16x8*)(qp + kc * 16);
    }

    f32x16 o0, o1;
#pragma unroll
    for (int r = 0; r < 16; ++r) { o0[r] = 0.f; o1[r] = 0.f; }
    float lrun = 0.f;

    const unsigned* mrow = mbits + ((size_t)b * Sc + qrow) * (Sc / 32);
    const unsigned short* kbase = kh + (size_t)bh * Sc * 64;
    const unsigned short* vbase = vt + (size_t)bh * 64 * Sc;

    const int kt0 = kh_ * 1024;
    uint4 pre[4];
    auto load_tile = [&](int kt) {
#pragma unroll
        for (int c = 0; c < 2; ++c) {       // K: 32 rows x 8 chunks
            int idx = st + c * 128, r = idx >> 3, cc = idx & 7;
            pre[c] = *(const uint4*)(kbase + (size_t)(kt + r) * 64 + cc * 8);
        }
#pragma unroll
        for (int c = 2; c < 4; ++c) {       // V: 64 dv x 4 chunks (32 keys)
            int j = st + c * 128 - 256, dv = j >> 2, cc = j & 3;
            pre[c] = *(const uint4*)(vbase + (size_t)dv * Sc + kt + cc * 8);
        }
    };

    load_tile(kt0);
    for (int i = 0; i < 32; ++i) {
        const int kt = kt0 + i * 32;
        __syncthreads();
#pragma unroll
        for (int c = 0; c < 2; ++c) {
            int idx = st + c * 128, r = idx >> 3, cc = idx & 7;
            *(uint4*)&Ks[r * 72 + cc * 8] = pre[c];
        }
#pragma unroll
        for (int c = 2; c < 4; ++c) {
            int j = st + c * 128 - 256, dv = j >> 2, cc = j & 3;
            *(uint4*)&Vs[dv * 40 + cc * 8] = pre[c];
        }
        __syncthreads();
        if (i < 31) load_tile(kt + 32);     // prefetch overlaps compute

        const unsigned mw = mrow[kt >> 5];

        // ---- S^T[key][q] = K · Q^T  (32 keys)
        f32x16 sv;
#pragma unroll
        for (int r = 0; r < 16; ++r) sv[r] = 0.f;
#pragma unroll
        for (int kc = 0; kc < 4; ++kc) {
            s16x8 kf = *(const s16x8*)&Ks[ln * 72 + kc * 16 + hf * 8];
            sv = __builtin_amdgcn_mfma_f32_32x32x16_bf16(kf, qf[kc], sv, 0, 0, 0);
        }

        // ---- mask + exp2 (no max: scores bounded), pack to bf16 pairs
        float ps = 0.f;
        unsigned pu[8];
#pragma unroll
        for (int r = 0; r < 16; r += 2) {
            int key0 = (r & 3) + 8 * (r >> 2) + 4 * hf;
            int key1 = ((r + 1) & 3) + 8 * ((r + 1) >> 2) + 4 * hf;
            float a = ((mw >> key0) & 1u) ? sv[r]     : -1e9f;
            float c = ((mw >> key1) & 1u) ? sv[r + 1] : -1e9f;
            float p0 = fexp2(a), p1 = fexp2(c);
            ps += p0 + p1;
            pu[r >> 1] = (unsigned)f2bf(p0) | ((unsigned)f2bf(p1) << 16);
        }
        lrun += ps;

        // ---- ctx^T[dv][q] += V · P^T  (B-frags are own regs, kappa-order)
#pragma unroll
        for (int kc = 0; kc < 2; ++kc) {
            uint4 uu; uu.x = pu[4*kc]; uu.y = pu[4*kc+1]; uu.z = pu[4*kc+2]; uu.w = pu[4*kc+3];
            s16x8 pf  = __builtin_bit_cast(s16x8, uu);
            s16x8 v0  = *(const s16x8*)&Vs[ln * 40 + kc * 16 + hf * 8];
            s16x8 v1  = *(const s16x8*)&Vs[(32 + ln) * 40 + kc * 16 + hf * 8];
            o0 = __builtin_amdgcn_mfma_f32_32x32x16_bf16(v0, pf, o0, 0, 0, 0);
            o1 = __builtin_amdgcn_mfma_f32_32x32x16_bf16(v1, pf, o1, 0, 0, 0);
        }
    }

    // l is per-hf partial (each lane saw 16 of 32 keys per tile)
    lrun += __shfl_xor(lrun, 32);

    // ---- cross-kh combine (linear: no max state). kh=1 -> LDS, kh=0 adds.
    __syncthreads();
    float* cs = (float*)smem4;                       // [2][64][36] floats
    float* my = cs + ((size_t)(g * 64 + lane)) * 36;
    if (kh_ == 1) {
#pragma unroll
        for (int r = 0; r < 4; ++r) {
            float4 a; a.x = o0[4*r]; a.y = o0[4*r+1]; a.z = o0[4*r+2]; a.w = o0[4*r+3];
            float4 c; c.x = o1[4*r]; c.y = o1[4*r+1]; c.z = o1[4*r+2]; c.w = o1[4*r+3];
            *(float4*)(my + 4 * r)      = a;
            *(float4*)(my + 16 + 4 * r) = c;
        }
        my[32] = lrun;
    }
    __syncthreads();
    if (kh_ == 0) {
        lrun += my[32];
        const float inv = 1.f / lrun;
#pragma unroll
        for (int r = 0; r < 4; ++r) {
            float4 a = *(const float4*)(my + 4 * r);
            float4 c = *(const float4*)(my + 16 + 4 * r);
            o0[4*r]   = (o0[4*r]   + a.x) * inv; o0[4*r+1] = (o0[4*r+1] + a.y) * inv;
            o0[4*r+2] = (o0[4*r+2] + a.z) * inv; o0[4*r+3] = (o0[4*r+3] + a.w) * inv;
            o1[4*r]   = (o1[4*r]   + c.x) * inv; o1[4*r+1] = (o1[4*r+1] + c.y) * inv;
            o1[4*r+2] = (o1[4*r+2] + c.z) * inv; o1[4*r+3] = (o1[4*r+3] + c.w) * inv;
        }
        // ctx bf16 [B,S,D]; dv = 8g' + 4hf + t (+32 for o1)
        unsigned short* op = ctx + ((size_t)(b * Sc + qrow)) * 512 + h * 64;
#pragma unroll
        for (int gg = 0; gg < 4; ++gg) {
            ushort4 a, c;
            a.x = f2bf(o0[gg*4+0]); a.y = f2bf(o0[gg*4+1]);
            a.z = f2bf(o0[gg*4+2]); a.w = f2bf(o0[gg*4+3]);
            c.x = f2bf(o1[gg*4+0]); c.y = f2bf(o1[gg*4+1]);
            c.z = f2bf(o1[gg*4+2]); c.w = f2bf(o1[gg*4+3]);
            *(ushort4*)(op + 8 * gg + 4 * hf)      = a;
            *(ushort4*)(op + 32 + 8 * gg + 4 * hf) = c;
        }
    }
}

// ---------------------------------------------------------------------------
extern "C" void kernel_launch(void* const* d_in, const int* in_sizes, int n_in,
                              void* d_out, int out_size, void* d_ws, size_t ws_size,
                              hipStream_t stream)
{
    (void)in_sizes; (void)n_in; (void)out_size; (void)ws_size;

    const float* q    = (const float*)d_in[0];
    const float* k    = (const float*)d_in[1];
    const float* v    = (const float*)d_in[2];
    const int*   mask = (const int*)  d_in[3];
    const float* Wq   = (const float*)d_in[4];
    const float* bq   = (const float*)d_in[5];
    const float* Wk   = (const float*)d_in[6];
    const float* bk   = (const float*)d_in[7];
    const float* Wv   = (const float*)d_in[8];
    const float* bv   = (const float*)d_in[9];
    const float* Wo   = (const float*)d_in[10];
    const float* bo   = (const float*)d_in[11];
    float* out = (float*)d_out;

    // workspace carve (bf16 unless noted); TEN = 4,194,304 elems
    constexpr size_t TEN = (size_t)Bc * Hc * Sc * DKc;
    char* p = (char*)d_ws;
    unsigned short* qb    = (unsigned short*)p;  p += TEN * 2;        // 8 MB  (q bf16)
    unsigned short* kb    = (unsigned short*)p;  p += TEN * 2;        // 8 MB
    unsigned short* vb    = (unsigned short*)p;  p += TEN * 2;        // 8 MB
    unsigned short* wqb   = (unsigned short*)p;  p += (size_t)Dc * Dc * 2;  // 0.5 MB
    unsigned short* wkb   = (unsigned short*)p;  p += (size_t)Dc * Dc * 2;
    unsigned short* wvb   = (unsigned short*)p;  p += (size_t)Dc * Dc * 2;
    unsigned short* wob   = (unsigned short*)p;  p += (size_t)Dc * Dc * 2;
    unsigned short* qh_bf = (unsigned short*)p;  p += TEN * 2;        // 8 MB
    unsigned short* kh_bf = (unsigned short*)p;  p += TEN * 2;
    unsigned short* vt_bf = (unsigned short*)p;  p += TEN * 2;
    unsigned short* ctx   = (unsigned short*)p;  p += TEN * 2;
    unsigned long long* mb64 = (unsigned long long*)p;                // 2 MB

    const int nwords = Bc * Sc * (Sc / 64);   // 262144

    dim3 bb(256);
    dim3 gg(Mc / 128, Dc / 64);   // (64, 8)

    pack_mask<<<dim3(512), bb, 0, stream>>>(mask, mb64, nwords);
    cvt4<<<dim3((int)(TEN / 4 / 256), 3), bb, 0, stream>>>(q, k, v, q, qb, kb, vb, qb,
                                                           (int)(TEN / 4));
    cvt4<<<dim3(Dc * Dc / 4 / 256, 4), bb, 0, stream>>>(Wq, Wk, Wv, Wo, wqb, wkb, wvb, wob,
                                                        Dc * Dc / 4);
    gemm_mfma<1><<<gg, bb, 0, stream>>>(qb, wqb, bq, qh_bf, SCALE_Q);
    gemm_mfma<1><<<gg, bb, 0, stream>>>(kb, wkb, bk, kh_bf, 1.0f);
    gemm_mfma<2><<<gg, bb, 0, stream>>>(vb, wvb, bv, vt_bf, 1.0f);
    attn_mfma<<<dim3(Sc / 64, Bc * Hc), bb, 0, stream>>>(qh_bf, kh_bf, vt_bf,
                                                         (const unsigned*)mb64, ctx);
    gemm_mfma<0><<<gg, bb, 0, stream>>>(ctx, wob, bo, out, 1.0f);
}

// Round 5
// 430.181 us; speedup vs baseline: 1.1738x; 1.1738x over previous
//
#include <hip/hip_runtime.h>
#include <math.h>

// Problem constants
constexpr int Bc  = 4;
constexpr int Sc  = 2048;
constexpr int Dc  = 512;
constexpr int Hc  = 8;
constexpr int DKc = 64;
constexpr int Mc  = Bc * Sc;   // 8192 rows

constexpr float SCALE_Q = 0.180336880111120426f;   // (1/8) * log2(e): /H quirk + exp2 base

typedef __attribute__((ext_vector_type(8)))  short s16x8;   // 8 bf16 MFMA frag
typedef __attribute__((ext_vector_type(4)))  float f32x4;   // 16x16 accumulator
typedef __attribute__((ext_vector_type(16))) float f32x16;  // 32x32 accumulator

__device__ __forceinline__ unsigned short f2bf(float f) {
    __bf16 h = (__bf16)f;                 // RNE convert
    return __builtin_bit_cast(unsigned short, h);
}

__device__ __forceinline__ float fexp2(float x) {
#if __has_builtin(__builtin_amdgcn_exp2f)
    return __builtin_amdgcn_exp2f(x);
#else
    return __expf(x * 0.6931471805599453f);
#endif
}

__device__ __forceinline__ uint4 pack8(float4 a, float4 b) {
    uint4 u;
    u.x = (unsigned)f2bf(a.x) | ((unsigned)f2bf(a.y) << 16);
    u.y = (unsigned)f2bf(a.z) | ((unsigned)f2bf(a.w) << 16);
    u.z = (unsigned)f2bf(b.x) | ((unsigned)f2bf(b.y) << 16);
    u.w = (unsigned)f2bf(b.z) | ((unsigned)f2bf(b.w) << 16);
    return u;
}

// ---------------------------------------------------------------------------
// mask [B,1,S,S] int32 -> keep-bit words: bit j of word w == (mask[w*64+j]!=0)
// ---------------------------------------------------------------------------
__global__ __launch_bounds__(256)
void pack_mask(const int* __restrict__ mask, unsigned long long* __restrict__ out,
               int nwords)
{
    int gw   = (blockIdx.x * blockDim.x + threadIdx.x) >> 6;
    int lane = threadIdx.x & 63;
    int nw   = (gridDim.x * blockDim.x) >> 6;
    for (int w = gw; w < nwords; w += nw) {
        int v = mask[(size_t)w * 64 + lane];
        unsigned long long bits = __ballot(v != 0);
        if (lane == 0) out[w] = bits;
    }
}

// ---------------------------------------------------------------------------
// fp32 -> bf16 elementwise, 4 tensors (blockIdx.y selects), n4 float4s each
// ---------------------------------------------------------------------------
__global__ __launch_bounds__(256)
void cvt4(const float* __restrict__ i0, const float* __restrict__ i1,
          const float* __restrict__ i2, const float* __restrict__ i3,
          unsigned short* __restrict__ o0, unsigned short* __restrict__ o1,
          unsigned short* __restrict__ o2, unsigned short* __restrict__ o3,
          int n4)
{
    const float* in; unsigned short* out;
    switch (blockIdx.y) {
        case 0: in = i0; out = o0; break;
        case 1: in = i1; out = o1; break;
        case 2: in = i2; out = o2; break;
        default: in = i3; out = o3; break;
    }
    int i = blockIdx.x * 256 + threadIdx.x;
    if (i < n4) {
        float4 v = ((const float4*)in)[i];
        ushort4 r;
        r.x = f2bf(v.x); r.y = f2bf(v.y); r.z = f2bf(v.z); r.w = f2bf(v.w);
        ((ushort4*)out)[i] = r;
    }
}

// ---------------------------------------------------------------------------
// 64x64-tile bf16-MFMA GEMM, out = (X[M,512] @ W[512,512]^T + bias)*scale.
// blockIdx.z selects among up to 3 independent problems (merged projections:
// one dispatch, 3072 blocks -> block-level TLP hides the per-iter chain).
// XBF=false: X fp32, converted to bf16 inside staging. XBF=true: X bf16.
// Double-buffered LDS, ONE barrier per k-iter; register prefetch.
// mode 0: fp32 flat [M,512]
// mode 1: bf16 head layout   [((b*H+h)*S+s)*64 + dk]
// mode 2: bf16 head transposed [((b*H+h)*64+dk)*S + swap23(s)]  (V: key-bit
//         swap makes attention's P B-frags lane-local)
// (256,3): cap ~170 VGPR -- round-2/round-4 lesson: never cap at 128 for
// ~100-reg kernels, the allocator spills catastrophically.
// ---------------------------------------------------------------------------
template<bool XBF>
__global__ __launch_bounds__(256, 3)
void gemm64(const void* __restrict__ x0, const void* __restrict__ x1,
            const void* __restrict__ x2,
            const unsigned short* __restrict__ w0, const unsigned short* __restrict__ w1,
            const unsigned short* __restrict__ w2,
            const float* __restrict__ b0, const float* __restrict__ b1,
            const float* __restrict__ b2,
            void* __restrict__ o0v, void* __restrict__ o1v, void* __restrict__ o2v,
            float s0, float s1, float s2, int m0, int m1, int m2)
{
    const void* Xv; const unsigned short* W; const float* bias; void* outv;
    float scale; int mode;
    switch (blockIdx.z) {
        case 0:  Xv = x0; W = w0; bias = b0; outv = o0v; scale = s0; mode = m0; break;
        case 1:  Xv = x1; W = w1; bias = b1; outv = o1v; scale = s1; mode = m1; break;
        default: Xv = x2; W = w2; bias = b2; outv = o2v; scale = s2; mode = m2; break;
    }

    __shared__ unsigned short Xs[2][64][72];
    __shared__ unsigned short Ws[2][64][72];

    const int tid = threadIdx.x;
    const int w = tid >> 6, lane = tid & 63, ln = lane & 15, qd = lane >> 4;
    const int wm = (w >> 1) * 32, wn = (w & 1) * 32;
    const int row0 = blockIdx.x * 64, col0 = blockIdx.y * 64;

    f32x4 acc[2][2];
#pragma unroll
    for (int mt = 0; mt < 2; ++mt)
#pragma unroll
        for (int nt = 0; nt < 2; ++nt) acc[mt][nt] = f32x4{0.f, 0.f, 0.f, 0.f};

    float4 xf[4]; uint4 xb[2]; uint4 wr[2];
    auto load = [&](int k0) {
#pragma unroll
        for (int c = 0; c < 2; ++c) {
            int u = tid + c * 256, r = u >> 3, c8 = u & 7;
            if (XBF) {
                xb[c] = *(const uint4*)((const unsigned short*)Xv +
                                        (size_t)(row0 + r) * 512 + k0 + c8 * 8);
            } else {
                const float* xp = (const float*)Xv + (size_t)(row0 + r) * 512 + k0 + c8 * 8;
                xf[2 * c]     = *(const float4*)xp;
                xf[2 * c + 1] = *(const float4*)(xp + 4);
            }
            wr[c] = *(const uint4*)(W + (size_t)(col0 + r) * 512 + k0 + c8 * 8);
        }
    };
    auto store = [&](int buf) {
#pragma unroll
        for (int c = 0; c < 2; ++c) {
            int u = tid + c * 256, r = u >> 3, c8 = u & 7;
            uint4 xv = XBF ? xb[c] : pack8(xf[2 * c], xf[2 * c + 1]);
            *(uint4*)&Xs[buf][r][c8 * 8] = xv;
            *(uint4*)&Ws[buf][r][c8 * 8] = wr[c];
        }
    };

    load(0);
    store(0);
    for (int k0 = 0; k0 < 512; k0 += 64) {
        const int buf = (k0 >> 6) & 1;
        __syncthreads();
        if (k0 + 64 < 512) load(k0 + 64);   // overlaps compute below
#pragma unroll
        for (int kc = 0; kc < 2; ++kc) {
            s16x8 af[2], bfr[2];
#pragma unroll
            for (int mt = 0; mt < 2; ++mt)
                af[mt] = *(const s16x8*)&Xs[buf][wm + mt * 16 + ln][kc * 32 + qd * 8];
#pragma unroll
            for (int nt = 0; nt < 2; ++nt)
                bfr[nt] = *(const s16x8*)&Ws[buf][wn + nt * 16 + ln][kc * 32 + qd * 8];
#pragma unroll
            for (int mt = 0; mt < 2; ++mt)
#pragma unroll
                for (int nt = 0; nt < 2; ++nt)
                    acc[mt][nt] = __builtin_amdgcn_mfma_f32_16x16x32_bf16(
                        af[mt], bfr[nt], acc[mt][nt], 0, 0, 0);
        }
        if (k0 + 64 < 512) store(buf ^ 1);
    }

    // epilogue: m = mbase + r (reg), n = col0+wn+nt*16+ln
#pragma unroll
    for (int nt = 0; nt < 2; ++nt) {
        const int n = col0 + wn + nt * 16 + ln;
        const float bz = bias[n];
#pragma unroll
        for (int mt = 0; mt < 2; ++mt) {
            const int mbase = row0 + wm + mt * 16 + qd * 4;
            if (mode == 0) {
                float* o = (float*)outv;
#pragma unroll
                for (int r = 0; r < 4; ++r)
                    o[(size_t)(mbase + r) * 512 + n] = acc[mt][nt][r] + bz;
            } else if (mode == 1) {
                unsigned short* o = (unsigned short*)outv;
                const int h = n >> 6, dk = n & 63;
#pragma unroll
                for (int r = 0; r < 4; ++r) {
                    int m = mbase + r, b = m >> 11, s = m & 2047;
                    o[((size_t)(b * Hc + h) * Sc + s) * 64 + dk] =
                        f2bf((acc[mt][nt][r] + bz) * scale);
                }
            } else {
                unsigned short* o = (unsigned short*)outv;
                const int h = n >> 6, dk = n & 63;
                const int b = mbase >> 11, sb = mbase & 2047;
                const int ss = (sb & ~12) | ((sb & 4) << 1) | ((sb & 8) >> 1); // swap bits 2,3
                ushort4 pk;
                pk.x = f2bf((acc[mt][nt][0] + bz) * scale);
                pk.y = f2bf((acc[mt][nt][1] + bz) * scale);
                pk.z = f2bf((acc[mt][nt][2] + bz) * scale);
                pk.w = f2bf((acc[mt][nt][3] + bz) * scale);
                *(ushort4*)(o + ((size_t)(b * Hc + h) * 64 + dk) * Sc + ss) = pk;
            }
        }
    }
}

// ---------------------------------------------------------------------------
// Split-K bf16 32x32x16-MFMA flash attention, max-free softmax.
// Grid (S/64, B*H), 256 thr = 4 waves = 2 q-groups x 2 key-halves.
// Math identical to round 4 (verified): p = exp2(masked s'), masked -> 0;
// PV B-frags are the lane's own p registers (V key axis swap23-permuted at
// projection); linear cross-half combine at end.
// NEW: (256,3) so ~105 live regs fit (no spill), double-buffered LDS with
// ONE barrier per 32-key iter, mask word prefetched with the tile.
// ---------------------------------------------------------------------------
__global__ __launch_bounds__(256, 3)
void attn_mfma(const unsigned short* __restrict__ qh, const unsigned short* __restrict__ kh,
               const unsigned short* __restrict__ vt, const unsigned* __restrict__ mbits,
               unsigned short* __restrict__ ctx)
{
    __shared__ uint4 smem4[2][19456 / 16];   // per buf: 2 kh-groups x (Ks 32x72 + Vs 64x40)

    const int bh = blockIdx.y, b = bh >> 3, h = bh & 7;
    const int q0 = blockIdx.x * 64;
    const int tid = threadIdx.x;
    const int w = tid >> 6;
    const int g = w >> 1;            // q-group
    const int kh_ = w & 1;           // key half
    const int lane = tid & 63, ln = lane & 31, hf = lane >> 5;
    const int qrow = q0 + g * 32 + ln;

    const int st = ((tid >> 7) << 6) | (tid & 63);   // staging id within kh-group

    // Q B-frags, resident
    s16x8 qf[4];
    {
        const unsigned short* qp = qh + ((size_t)bh * Sc + qrow) * 64 + hf * 8;
#pragma unroll
        for (int kc = 0; kc < 4; ++kc) qf[kc] = *(const s16x8*)(qp + kc * 16);
    }

    f32x16 o0, o1;
#pragma unroll
    for (int r = 0; r < 16; ++r) { o0[r] = 0.f; o1[r] = 0.f; }
    float lrun = 0.f;

    const unsigned* mrow = mbits + ((size_t)b * Sc + qrow) * (Sc / 32);
    const unsigned short* kbase = kh + (size_t)bh * Sc * 64;
    const unsigned short* vbase = vt + (size_t)bh * 64 * Sc;

    const int kt0 = kh_ * 1024;
    uint4 pre[4];
    auto load_tile = [&](int kt) {
#pragma unroll
        for (int c = 0; c < 2; ++c) {       // K: 32 rows x 8 chunks
            int idx = st + c * 128, r = idx >> 3, cc = idx & 7;
            pre[c] = *(const uint4*)(kbase + (size_t)(kt + r) * 64 + cc * 8);
        }
#pragma unroll
        for (int c = 2; c < 4; ++c) {       // V: 64 dv x 4 chunks (32 keys)
            int j = st + c * 128 - 256, dv = j >> 2, cc = j & 3;
            pre[c] = *(const uint4*)(vbase + (size_t)dv * Sc + kt + cc * 8);
        }
    };
    auto store_tile = [&](int buf) {
        unsigned short* Ks = (unsigned short*)((char*)smem4[buf] + kh_ * 9728);
        unsigned short* Vs = Ks + 4608 / 2;
#pragma unroll
        for (int c = 0; c < 2; ++c) {
            int idx = st + c * 128, r = idx >> 3, cc = idx & 7;
            *(uint4*)&Ks[r * 72 + cc * 8] = pre[c];
        }
#pragma unroll
        for (int c = 2; c < 4; ++c) {
            int j = st + c * 128 - 256, dv = j >> 2, cc = j & 3;
            *(uint4*)&Vs[dv * 40 + cc * 8] = pre[c];
        }
    };

    load_tile(kt0);
    unsigned mwn = mrow[kt0 >> 5];
    store_tile(0);

    for (int i = 0; i < 32; ++i) {
        const int kt = kt0 + i * 32;
        const int buf = i & 1;
        __syncthreads();
        const unsigned mw = mwn;
        if (i < 31) { load_tile(kt + 32); mwn = mrow[(kt + 32) >> 5]; }

        const unsigned short* Ks = (const unsigned short*)((char*)smem4[buf] + kh_ * 9728);
        const unsigned short* Vs = Ks + 4608 / 2;

        // ---- S^T[key][q] = K · Q^T  (32 keys)
        f32x16 sv;
#pragma unroll
        for (int r = 0; r < 16; ++r) sv[r] = 0.f;
#pragma unroll
        for (int kc = 0; kc < 4; ++kc) {
            s16x8 kf = *(const s16x8*)&Ks[ln * 72 + kc * 16 + hf * 8];
            sv = __builtin_amdgcn_mfma_f32_32x32x16_bf16(kf, qf[kc], sv, 0, 0, 0);
        }

        // ---- mask + exp2 (no max: scores bounded), pack to bf16 pairs
        float ps = 0.f;
        unsigned pu[8];
#pragma unroll
        for (int r = 0; r < 16; r += 2) {
            int key0 = (r & 3) + 8 * (r >> 2) + 4 * hf;
            int key1 = ((r + 1) & 3) + 8 * ((r + 1) >> 2) + 4 * hf;
            float a = ((mw >> key0) & 1u) ? sv[r]     : -1e9f;
            float c = ((mw >> key1) & 1u) ? sv[r + 1] : -1e9f;
            float p0 = fexp2(a), p1 = fexp2(c);
            ps += p0 + p1;
            pu[r >> 1] = (unsigned)f2bf(p0) | ((unsigned)f2bf(p1) << 16);
        }
        lrun += ps;

        // ---- ctx^T[dv][q] += V · P^T  (B-frags are own regs, kappa-order)
#pragma unroll
        for (int kc = 0; kc < 2; ++kc) {
            uint4 uu; uu.x = pu[4*kc]; uu.y = pu[4*kc+1]; uu.z = pu[4*kc+2]; uu.w = pu[4*kc+3];
            s16x8 pf  = __builtin_bit_cast(s16x8, uu);
            s16x8 v0  = *(const s16x8*)&Vs[ln * 40 + kc * 16 + hf * 8];
            s16x8 v1  = *(const s16x8*)&Vs[(32 + ln) * 40 + kc * 16 + hf * 8];
            o0 = __builtin_amdgcn_mfma_f32_32x32x16_bf16(v0, pf, o0, 0, 0, 0);
            o1 = __builtin_amdgcn_mfma_f32_32x32x16_bf16(v1, pf, o1, 0, 0, 0);
        }

        if (i < 31) store_tile(buf ^ 1);
    }

    // l is per-hf partial (each lane saw 16 of 32 keys per tile)
    lrun += __shfl_xor(lrun, 32);

    // ---- cross-kh combine (linear: no max state). kh=1 -> LDS, kh=0 adds.
    __syncthreads();
    float* cs = (float*)smem4[0];                    // [2][64][36] floats, 18432 B
    float* my = cs + ((size_t)(g * 64 + lane)) * 36;
    if (kh_ == 1) {
#pragma unroll
        for (int r = 0; r < 4; ++r) {
            float4 a; a.x = o0[4*r]; a.y = o0[4*r+1]; a.z = o0[4*r+2]; a.w = o0[4*r+3];
            float4 c; c.x = o1[4*r]; c.y = o1[4*r+1]; c.z = o1[4*r+2]; c.w = o1[4*r+3];
            *(float4*)(my + 4 * r)      = a;
            *(float4*)(my + 16 + 4 * r) = c;
        }
        my[32] = lrun;
    }
    __syncthreads();
    if (kh_ == 0) {
        lrun += my[32];
        const float inv = 1.f / lrun;
#pragma unroll
        for (int r = 0; r < 4; ++r) {
            float4 a = *(const float4*)(my + 4 * r);
            float4 c = *(const float4*)(my + 16 + 4 * r);
            o0[4*r]   = (o0[4*r]   + a.x) * inv; o0[4*r+1] = (o0[4*r+1] + a.y) * inv;
            o0[4*r+2] = (o0[4*r+2] + a.z) * inv; o0[4*r+3] = (o0[4*r+3] + a.w) * inv;
            o1[4*r]   = (o1[4*r]   + c.x) * inv; o1[4*r+1] = (o1[4*r+1] + c.y) * inv;
            o1[4*r+2] = (o1[4*r+2] + c.z) * inv; o1[4*r+3] = (o1[4*r+3] + c.w) * inv;
        }
        // ctx bf16 [B,S,D]; dv = 8g' + 4hf + t (+32 for o1)
        unsigned short* op = ctx + ((size_t)(b * Sc + qrow)) * 512 + h * 64;
#pragma unroll
        for (int gg = 0; gg < 4; ++gg) {
            ushort4 a, c;
            a.x = f2bf(o0[gg*4+0]); a.y = f2bf(o0[gg*4+1]);
            a.z = f2bf(o0[gg*4+2]); a.w = f2bf(o0[gg*4+3]);
            c.x = f2bf(o1[gg*4+0]); c.y = f2bf(o1[gg*4+1]);
            c.z = f2bf(o1[gg*4+2]); c.w = f2bf(o1[gg*4+3]);
            *(ushort4*)(op + 8 * gg + 4 * hf)      = a;
            *(ushort4*)(op + 32 + 8 * gg + 4 * hf) = c;
        }
    }
}

// ---------------------------------------------------------------------------
extern "C" void kernel_launch(void* const* d_in, const int* in_sizes, int n_in,
                              void* d_out, int out_size, void* d_ws, size_t ws_size,
                              hipStream_t stream)
{
    (void)in_sizes; (void)n_in; (void)out_size; (void)ws_size;

    const float* q    = (const float*)d_in[0];
    const float* k    = (const float*)d_in[1];
    const float* v    = (const float*)d_in[2];
    const int*   mask = (const int*)  d_in[3];
    const float* Wq   = (const float*)d_in[4];
    const float* bq   = (const float*)d_in[5];
    const float* Wk   = (const float*)d_in[6];
    const float* bk   = (const float*)d_in[7];
    const float* Wv   = (const float*)d_in[8];
    const float* bv   = (const float*)d_in[9];
    const float* Wo   = (const float*)d_in[10];
    const float* bo   = (const float*)d_in[11];
    float* out = (float*)d_out;

    // workspace carve; TEN = 4,194,304 elems
    constexpr size_t TEN = (size_t)Bc * Hc * Sc * DKc;
    char* p = (char*)d_ws;
    unsigned short* wqb   = (unsigned short*)p;  p += (size_t)Dc * Dc * 2;  // 0.5 MB
    unsigned short* wkb   = (unsigned short*)p;  p += (size_t)Dc * Dc * 2;
    unsigned short* wvb   = (unsigned short*)p;  p += (size_t)Dc * Dc * 2;
    unsigned short* wob   = (unsigned short*)p;  p += (size_t)Dc * Dc * 2;
    unsigned short* qh_bf = (unsigned short*)p;  p += TEN * 2;              // 8 MB
    unsigned short* kh_bf = (unsigned short*)p;  p += TEN * 2;
    unsigned short* vt_bf = (unsigned short*)p;  p += TEN * 2;
    unsigned short* ctx   = (unsigned short*)p;  p += TEN * 2;
    unsigned long long* mb64 = (unsigned long long*)p;                      // 2 MB

    const int nwords = Bc * Sc * (Sc / 64);   // 262144

    dim3 bb(256);

    pack_mask<<<dim3(512), bb, 0, stream>>>(mask, mb64, nwords);
    cvt4<<<dim3(Dc * Dc / 4 / 256, 4), bb, 0, stream>>>(Wq, Wk, Wv, Wo, wqb, wkb, wvb, wob,
                                                        Dc * Dc / 4);
    // merged Q/K/V projections: one dispatch, 3072 blocks
    gemm64<false><<<dim3(Mc / 64, Dc / 64, 3), bb, 0, stream>>>(
        q, k, v, wqb, wkb, wvb, bq, bk, bv, qh_bf, kh_bf, vt_bf,
        SCALE_Q, 1.0f, 1.0f, 1, 1, 2);
    attn_mfma<<<dim3(Sc / 64, Bc * Hc), bb, 0, stream>>>(qh_bf, kh_bf, vt_bf,
                                                         (const unsigned*)mb64, ctx);
    gemm64<true><<<dim3(Mc / 64, Dc / 64, 1), bb, 0, stream>>>(
        ctx, ctx, ctx, wob, wob, wob, bo, bo, bo, out, out, out,
        1.0f, 1.0f, 1.0f, 0, 0, 0);
}

// Round 6
// 430.017 us; speedup vs baseline: 1.1743x; 1.0004x over previous
//
#include <hip/hip_runtime.h>
#include <math.h>

// Problem constants
constexpr int Bc  = 4;
constexpr int Sc  = 2048;
constexpr int Dc  = 512;
constexpr int Hc  = 8;
constexpr int DKc = 64;
constexpr int Mc  = Bc * Sc;   // 8192 rows

constexpr float SCALE_Q = 0.180336880111120426f;   // (1/8) * log2(e): /H quirk + exp2 base

typedef __attribute__((ext_vector_type(8)))  short s16x8;   // 8 bf16 MFMA frag
typedef __attribute__((ext_vector_type(4)))  float f32x4;   // 16x16 accumulator
typedef __attribute__((ext_vector_type(16))) float f32x16;  // 32x32 accumulator

__device__ __forceinline__ unsigned short f2bf(float f) {
    __bf16 h = (__bf16)f;                 // RNE convert
    return __builtin_bit_cast(unsigned short, h);
}

__device__ __forceinline__ float fexp2(float x) {
#if __has_builtin(__builtin_amdgcn_exp2f)
    return __builtin_amdgcn_exp2f(x);
#else
    return __expf(x * 0.6931471805599453f);
#endif
}

__device__ __forceinline__ uint4 pack8(float4 a, float4 b) {
    uint4 u;
    u.x = (unsigned)f2bf(a.x) | ((unsigned)f2bf(a.y) << 16);
    u.y = (unsigned)f2bf(a.z) | ((unsigned)f2bf(a.w) << 16);
    u.z = (unsigned)f2bf(b.x) | ((unsigned)f2bf(b.y) << 16);
    u.w = (unsigned)f2bf(b.z) | ((unsigned)f2bf(b.w) << 16);
    return u;
}

// ---------------------------------------------------------------------------
// mask [B,1,S,S] int32 -> keep-bit words: bit j of word w == (mask[w*64+j]!=0)
// ---------------------------------------------------------------------------
__global__ __launch_bounds__(256)
void pack_mask(const int* __restrict__ mask, unsigned long long* __restrict__ out,
               int nwords)
{
    int gw   = (blockIdx.x * blockDim.x + threadIdx.x) >> 6;
    int lane = threadIdx.x & 63;
    int nw   = (gridDim.x * blockDim.x) >> 6;
    for (int w = gw; w < nwords; w += nw) {
        int v = mask[(size_t)w * 64 + lane];
        unsigned long long bits = __ballot(v != 0);
        if (lane == 0) out[w] = bits;
    }
}

// ---------------------------------------------------------------------------
// fp32 -> bf16 elementwise, 4 tensors (blockIdx.y selects), n4 float4s each
// ---------------------------------------------------------------------------
__global__ __launch_bounds__(256)
void cvt4(const float* __restrict__ i0, const float* __restrict__ i1,
          const float* __restrict__ i2, const float* __restrict__ i3,
          unsigned short* __restrict__ o0, unsigned short* __restrict__ o1,
          unsigned short* __restrict__ o2, unsigned short* __restrict__ o3,
          int n4)
{
    const float* in; unsigned short* out;
    switch (blockIdx.y) {
        case 0: in = i0; out = o0; break;
        case 1: in = i1; out = o1; break;
        case 2: in = i2; out = o2; break;
        default: in = i3; out = o3; break;
    }
    int i = blockIdx.x * 256 + threadIdx.x;
    if (i < n4) {
        float4 v = ((const float4*)in)[i];
        ushort4 r;
        r.x = f2bf(v.x); r.y = f2bf(v.y); r.z = f2bf(v.z); r.w = f2bf(v.w);
        ((ushort4*)out)[i] = r;
    }
}

// ---------------------------------------------------------------------------
// 128x64-tile bf16-MFMA GEMM: out = (X[M,512] @ W[512,512]^T + bias)*scale.
// blockIdx.z selects among up to 3 independent problems.
// XOR-swizzled UNPADDED LDS rows (64 shorts): element (r, chunk*8+off) lives
// at r*64 + ((chunk ^ (r&7))*8 + off. Self-consistent write/read; spreads
// b128 frag reads across all 8 bank-quads (same as +8 padding) but LDS/block
// is 48 KB -> 3 blocks/CU at (256,3). Reg footprint ~107 (fits 170 cap:
// rounds 2/4/5 proved the allocator spills catastrophically when total
// VGPR+AGPR exceeds the launch-bounds cap; here accumulator is only 32).
// Double-buffered LDS, ONE barrier per k-iter; bf16 conversion done at load
// time (XBF=false) so prefetch regs are uint4 not float4.
// mode 0: fp32 flat [M,512]
// mode 1: bf16 head layout   [((b*H+h)*S+s)*64 + dk]
// mode 2: bf16 head transposed [((b*H+h)*64+dk)*S + swap23(s)]
// ---------------------------------------------------------------------------
template<bool XBF>
__global__ __launch_bounds__(256, 3)
void gemm128(const void* __restrict__ x0, const void* __restrict__ x1,
             const void* __restrict__ x2,
             const unsigned short* __restrict__ w0, const unsigned short* __restrict__ w1,
             const unsigned short* __restrict__ w2,
             const float* __restrict__ b0, const float* __restrict__ b1,
             const float* __restrict__ b2,
             void* __restrict__ o0v, void* __restrict__ o1v, void* __restrict__ o2v,
             float s0, float s1, float s2, int m0, int m1, int m2)
{
    const void* Xv; const unsigned short* W; const float* bias; void* outv;
    float scale; int mode;
    switch (blockIdx.z) {
        case 0:  Xv = x0; W = w0; bias = b0; outv = o0v; scale = s0; mode = m0; break;
        case 1:  Xv = x1; W = w1; bias = b1; outv = o1v; scale = s1; mode = m1; break;
        default: Xv = x2; W = w2; bias = b2; outv = o2v; scale = s2; mode = m2; break;
    }

    __shared__ unsigned short Xs[2][128 * 64];
    __shared__ unsigned short Ws[2][64 * 64];

    const int tid = threadIdx.x;
    const int w = tid >> 6, lane = tid & 63, ln = lane & 15, qd = lane >> 4;
    const int wm = (w >> 1) * 64, wn = (w & 1) * 32;
    const int row0 = blockIdx.x * 128, col0 = blockIdx.y * 64;

    f32x4 acc[4][2];
#pragma unroll
    for (int mt = 0; mt < 4; ++mt)
#pragma unroll
        for (int nt = 0; nt < 2; ++nt) acc[mt][nt] = f32x4{0.f, 0.f, 0.f, 0.f};

    uint4 xb[4], wr[2];
    auto load = [&](int k0) {
#pragma unroll
        for (int c = 0; c < 4; ++c) {
            int u = tid + c * 256, r = u >> 3, c8 = u & 7;
            if (XBF) {
                xb[c] = *(const uint4*)((const unsigned short*)Xv +
                                        (size_t)(row0 + r) * 512 + k0 + c8 * 8);
            } else {
                const float* xp = (const float*)Xv + (size_t)(row0 + r) * 512 + k0 + c8 * 8;
                xb[c] = pack8(*(const float4*)xp, *(const float4*)(xp + 4));
            }
        }
#pragma unroll
        for (int c = 0; c < 2; ++c) {
            int u = tid + c * 256, r = u >> 3, c8 = u & 7;
            wr[c] = *(const uint4*)(W + (size_t)(col0 + r) * 512 + k0 + c8 * 8);
        }
    };
    auto store = [&](int buf) {
#pragma unroll
        for (int c = 0; c < 4; ++c) {
            int u = tid + c * 256, r = u >> 3, c8 = u & 7;
            *(uint4*)&Xs[buf][r * 64 + ((c8 ^ (r & 7)) * 8)] = xb[c];
        }
#pragma unroll
        for (int c = 0; c < 2; ++c) {
            int u = tid + c * 256, r = u >> 3, c8 = u & 7;
            *(uint4*)&Ws[buf][r * 64 + ((c8 ^ (r & 7)) * 8)] = wr[c];
        }
    };

    load(0);
    store(0);
    for (int k0 = 0; k0 < 512; k0 += 64) {
        const int buf = (k0 >> 6) & 1;
        __syncthreads();
        if (k0 + 64 < 512) load(k0 + 64);   // overlaps compute below
#pragma unroll
        for (int kc = 0; kc < 2; ++kc) {
            s16x8 af[4], bfr[2];
#pragma unroll
            for (int mt = 0; mt < 4; ++mt) {
                int r = wm + mt * 16 + ln;   // r&7 == ln&7 (wm, mt*16 are mult of 8)
                af[mt] = *(const s16x8*)&Xs[buf][r * 64 + (((kc * 4 + qd) ^ (ln & 7)) * 8)];
            }
#pragma unroll
            for (int nt = 0; nt < 2; ++nt) {
                int r = wn + nt * 16 + ln;
                bfr[nt] = *(const s16x8*)&Ws[buf][r * 64 + (((kc * 4 + qd) ^ (ln & 7)) * 8)];
            }
#pragma unroll
            for (int mt = 0; mt < 4; ++mt)
#pragma unroll
                for (int nt = 0; nt < 2; ++nt)
                    acc[mt][nt] = __builtin_amdgcn_mfma_f32_16x16x32_bf16(
                        af[mt], bfr[nt], acc[mt][nt], 0, 0, 0);
        }
        if (k0 + 64 < 512) store(buf ^ 1);
    }

    // epilogue: m = mbase + r (reg), n = col0+wn+nt*16+ln
#pragma unroll
    for (int nt = 0; nt < 2; ++nt) {
        const int n = col0 + wn + nt * 16 + ln;
        const float bz = bias[n];
#pragma unroll
        for (int mt = 0; mt < 4; ++mt) {
            const int mbase = row0 + wm + mt * 16 + qd * 4;
            if (mode == 0) {
                float* o = (float*)outv;
#pragma unroll
                for (int r = 0; r < 4; ++r)
                    o[(size_t)(mbase + r) * 512 + n] = acc[mt][nt][r] + bz;
            } else if (mode == 1) {
                unsigned short* o = (unsigned short*)outv;
                const int h = n >> 6, dk = n & 63;
#pragma unroll
                for (int r = 0; r < 4; ++r) {
                    int m = mbase + r, b = m >> 11, s = m & 2047;
                    o[((size_t)(b * Hc + h) * Sc + s) * 64 + dk] =
                        f2bf((acc[mt][nt][r] + bz) * scale);
                }
            } else {
                unsigned short* o = (unsigned short*)outv;
                const int h = n >> 6, dk = n & 63;
                const int b = mbase >> 11, sb = mbase & 2047;
                const int ss = (sb & ~12) | ((sb & 4) << 1) | ((sb & 8) >> 1); // swap bits 2,3
                ushort4 pk;
                pk.x = f2bf((acc[mt][nt][0] + bz) * scale);
                pk.y = f2bf((acc[mt][nt][1] + bz) * scale);
                pk.z = f2bf((acc[mt][nt][2] + bz) * scale);
                pk.w = f2bf((acc[mt][nt][3] + bz) * scale);
                *(ushort4*)(o + ((size_t)(b * Hc + h) * 64 + dk) * Sc + ss) = pk;
            }
        }
    }
}

// ---------------------------------------------------------------------------
// Split-K bf16 32x32x16-MFMA flash attention, max-free softmax.
// Grid (S/64, B*H), 256 thr = 4 waves = 2 q-groups x 2 key-halves.
// Math proven (r4/r5): p = exp2(masked s'), masked -> 0; PV B-frags are the
// lane's own p registers (V key axis swap23-permuted at projection); linear
// cross-half combine. Double-buffered LDS, one barrier/iter.
// (256,2): this kernel's total VGPR+AGPR footprint is ~160; capping at 128
// (w=4) or 170 (w=3) made the allocator spill 245-498 MB to scratch
// (r4/r5 counters). 256-reg cap is the only no-spill point (r3 evidence).
// ---------------------------------------------------------------------------
__global__ __launch_bounds__(256, 2)
void attn_mfma(const unsigned short* __restrict__ qh, const unsigned short* __restrict__ kh,
               const unsigned short* __restrict__ vt, const unsigned* __restrict__ mbits,
               unsigned short* __restrict__ ctx)
{
    __shared__ uint4 smem4[2][19456 / 16];   // per buf: 2 kh-groups x (Ks 32x72 + Vs 64x40)

    const int bh = blockIdx.y, b = bh >> 3, h = bh & 7;
    const int q0 = blockIdx.x * 64;
    const int tid = threadIdx.x;
    const int w = tid >> 6;
    const int g = w >> 1;            // q-group
    const int kh_ = w & 1;           // key half
    const int lane = tid & 63, ln = lane & 31, hf = lane >> 5;
    const int qrow = q0 + g * 32 + ln;

    const int st = ((tid >> 7) << 6) | (tid & 63);   // staging id within kh-group

    // Q B-frags, resident
    s16x8 qf[4];
    {
        const unsigned short* qp = qh + ((size_t)bh * Sc + qrow) * 64 + hf * 8;
#pragma unroll
        for (int kc = 0; kc < 4; ++kc) qf[kc] = *(const s16x8*)(qp + kc * 16);
    }

    f32x16 o0, o1;
#pragma unroll
    for (int r = 0; r < 16; ++r) { o0[r] = 0.f; o1[r] = 0.f; }
    float lrun = 0.f;

    const unsigned* mrow = mbits + ((size_t)b * Sc + qrow) * (Sc / 32);
    const unsigned short* kbase = kh + (size_t)bh * Sc * 64;
    const unsigned short* vbase = vt + (size_t)bh * 64 * Sc;

    const int kt0 = kh_ * 1024;
    uint4 pre[4];
    auto load_tile = [&](int kt) {
#pragma unroll
        for (int c = 0; c < 2; ++c) {       // K: 32 rows x 8 chunks
            int idx = st + c * 128, r = idx >> 3, cc = idx & 7;
            pre[c] = *(const uint4*)(kbase + (size_t)(kt + r) * 64 + cc * 8);
        }
#pragma unroll
        for (int c = 2; c < 4; ++c) {       // V: 64 dv x 4 chunks (32 keys)
            int j = st + c * 128 - 256, dv = j >> 2, cc = j & 3;
            pre[c] = *(const uint4*)(vbase + (size_t)dv * Sc + kt + cc * 8);
        }
    };
    auto store_tile = [&](int buf) {
        unsigned short* Ks = (unsigned short*)((char*)smem4[buf] + kh_ * 9728);
        unsigned short* Vs = Ks + 4608 / 2;
#pragma unroll
        for (int c = 0; c < 2; ++c) {
            int idx = st + c * 128, r = idx >> 3, cc = idx & 7;
            *(uint4*)&Ks[r * 72 + cc * 8] = pre[c];
        }
#pragma unroll
        for (int c = 2; c < 4; ++c) {
            int j = st + c * 128 - 256, dv = j >> 2, cc = j & 3;
            *(uint4*)&Vs[dv * 40 + cc * 8] = pre[c];
        }
    };

    load_tile(kt0);
    unsigned mwn = mrow[kt0 >> 5];
    store_tile(0);

    for (int i = 0; i < 32; ++i) {
        const int kt = kt0 + i * 32;
        const int buf = i & 1;
        __syncthreads();
        const unsigned mw = mwn;
        if (i < 31) { load_tile(kt + 32); mwn = mrow[(kt + 32) >> 5]; }

        const unsigned short* Ks = (const unsigned short*)((char*)smem4[buf] + kh_ * 9728);
        const unsigned short* Vs = Ks + 4608 / 2;

        // ---- S^T[key][q] = K · Q^T  (32 keys)
        f32x16 sv;
#pragma unroll
        for (int r = 0; r < 16; ++r) sv[r] = 0.f;
#pragma unroll
        for (int kc = 0; kc < 4; ++kc) {
            s16x8 kf = *(const s16x8*)&Ks[ln * 72 + kc * 16 + hf * 8];
            sv = __builtin_amdgcn_mfma_f32_32x32x16_bf16(kf, qf[kc], sv, 0, 0, 0);
        }

        // ---- mask + exp2 (no max: scores bounded), pack to bf16 pairs
        float ps = 0.f;
        unsigned pu[8];
#pragma unroll
        for (int r = 0; r < 16; r += 2) {
            int key0 = (r & 3) + 8 * (r >> 2) + 4 * hf;
            int key1 = ((r + 1) & 3) + 8 * ((r + 1) >> 2) + 4 * hf;
            float a = ((mw >> key0) & 1u) ? sv[r]     : -1e9f;
            float c = ((mw >> key1) & 1u) ? sv[r + 1] : -1e9f;
            float p0 = fexp2(a), p1 = fexp2(c);
            ps += p0 + p1;
            pu[r >> 1] = (unsigned)f2bf(p0) | ((unsigned)f2bf(p1) << 16);
        }
        lrun += ps;

        // ---- ctx^T[dv][q] += V · P^T  (B-frags are own regs, kappa-order)
#pragma unroll
        for (int kc = 0; kc < 2; ++kc) {
            uint4 uu; uu.x = pu[4*kc]; uu.y = pu[4*kc+1]; uu.z = pu[4*kc+2]; uu.w = pu[4*kc+3];
            s16x8 pf  = __builtin_bit_cast(s16x8, uu);
            s16x8 v0  = *(const s16x8*)&Vs[ln * 40 + kc * 16 + hf * 8];
            s16x8 v1  = *(const s16x8*)&Vs[(32 + ln) * 40 + kc * 16 + hf * 8];
            o0 = __builtin_amdgcn_mfma_f32_32x32x16_bf16(v0, pf, o0, 0, 0, 0);
            o1 = __builtin_amdgcn_mfma_f32_32x32x16_bf16(v1, pf, o1, 0, 0, 0);
        }

        if (i < 31) store_tile(buf ^ 1);
    }

    // l is per-hf partial (each lane saw 16 of 32 keys per tile)
    lrun += __shfl_xor(lrun, 32);

    // ---- cross-kh combine (linear: no max state). kh=1 -> LDS, kh=0 adds.
    __syncthreads();
    float* cs = (float*)smem4[0];                    // [2][64][36] floats, 18432 B
    float* my = cs + ((size_t)(g * 64 + lane)) * 36;
    if (kh_ == 1) {
#pragma unroll
        for (int r = 0; r < 4; ++r) {
            float4 a; a.x = o0[4*r]; a.y = o0[4*r+1]; a.z = o0[4*r+2]; a.w = o0[4*r+3];
            float4 c; c.x = o1[4*r]; c.y = o1[4*r+1]; c.z = o1[4*r+2]; c.w = o1[4*r+3];
            *(float4*)(my + 4 * r)      = a;
            *(float4*)(my + 16 + 4 * r) = c;
        }
        my[32] = lrun;
    }
    __syncthreads();
    if (kh_ == 0) {
        lrun += my[32];
        const float inv = 1.f / lrun;
#pragma unroll
        for (int r = 0; r < 4; ++r) {
            float4 a = *(const float4*)(my + 4 * r);
            float4 c = *(const float4*)(my + 16 + 4 * r);
            o0[4*r]   = (o0[4*r]   + a.x) * inv; o0[4*r+1] = (o0[4*r+1] + a.y) * inv;
            o0[4*r+2] = (o0[4*r+2] + a.z) * inv; o0[4*r+3] = (o0[4*r+3] + a.w) * inv;
            o1[4*r]   = (o1[4*r]   + c.x) * inv; o1[4*r+1] = (o1[4*r+1] + c.y) * inv;
            o1[4*r+2] = (o1[4*r+2] + c.z) * inv; o1[4*r+3] = (o1[4*r+3] + c.w) * inv;
        }
        // ctx bf16 [B,S,D]; dv = 8g' + 4hf + t (+32 for o1)
        unsigned short* op = ctx + ((size_t)(b * Sc + qrow)) * 512 + h * 64;
#pragma unroll
        for (int gg = 0; gg < 4; ++gg) {
            ushort4 a, c;
            a.x = f2bf(o0[gg*4+0]); a.y = f2bf(o0[gg*4+1]);
            a.z = f2bf(o0[gg*4+2]); a.w = f2bf(o0[gg*4+3]);
            c.x = f2bf(o1[gg*4+0]); c.y = f2bf(o1[gg*4+1]);
            c.z = f2bf(o1[gg*4+2]); c.w = f2bf(o1[gg*4+3]);
            *(ushort4*)(op + 8 * gg + 4 * hf)      = a;
            *(ushort4*)(op + 32 + 8 * gg + 4 * hf) = c;
        }
    }
}

// ---------------------------------------------------------------------------
extern "C" void kernel_launch(void* const* d_in, const int* in_sizes, int n_in,
                              void* d_out, int out_size, void* d_ws, size_t ws_size,
                              hipStream_t stream)
{
    (void)in_sizes; (void)n_in; (void)out_size; (void)ws_size;

    const float* q    = (const float*)d_in[0];
    const float* k    = (const float*)d_in[1];
    const float* v    = (const float*)d_in[2];
    const int*   mask = (const int*)  d_in[3];
    const float* Wq   = (const float*)d_in[4];
    const float* bq   = (const float*)d_in[5];
    const float* Wk   = (const float*)d_in[6];
    const float* bk   = (const float*)d_in[7];
    const float* Wv   = (const float*)d_in[8];
    const float* bv   = (const float*)d_in[9];
    const float* Wo   = (const float*)d_in[10];
    const float* bo   = (const float*)d_in[11];
    float* out = (float*)d_out;

    // workspace carve; TEN = 4,194,304 elems
    constexpr size_t TEN = (size_t)Bc * Hc * Sc * DKc;
    char* p = (char*)d_ws;
    unsigned short* wqb   = (unsigned short*)p;  p += (size_t)Dc * Dc * 2;  // 0.5 MB
    unsigned short* wkb   = (unsigned short*)p;  p += (size_t)Dc * Dc * 2;
    unsigned short* wvb   = (unsigned short*)p;  p += (size_t)Dc * Dc * 2;
    unsigned short* wob   = (unsigned short*)p;  p += (size_t)Dc * Dc * 2;
    unsigned short* qh_bf = (unsigned short*)p;  p += TEN * 2;              // 8 MB
    unsigned short* kh_bf = (unsigned short*)p;  p += TEN * 2;
    unsigned short* vt_bf = (unsigned short*)p;  p += TEN * 2;
    unsigned short* ctx   = (unsigned short*)p;  p += TEN * 2;
    unsigned long long* mb64 = (unsigned long long*)p;                      // 2 MB

    const int nwords = Bc * Sc * (Sc / 64);   // 262144

    dim3 bb(256);

    pack_mask<<<dim3(512), bb, 0, stream>>>(mask, mb64, nwords);
    cvt4<<<dim3(Dc * Dc / 4 / 256, 4), bb, 0, stream>>>(Wq, Wk, Wv, Wo, wqb, wkb, wvb, wob,
                                                        Dc * Dc / 4);
    // merged Q/K/V projections: one dispatch, 1536 blocks, 3 blocks/CU
    gemm128<false><<<dim3(Mc / 128, Dc / 64, 3), bb, 0, stream>>>(
        q, k, v, wqb, wkb, wvb, bq, bk, bv, qh_bf, kh_bf, vt_bf,
        SCALE_Q, 1.0f, 1.0f, 1, 1, 2);
    attn_mfma<<<dim3(Sc / 64, Bc * Hc), bb, 0, stream>>>(qh_bf, kh_bf, vt_bf,
                                                         (const unsigned*)mb64, ctx);
    gemm128<true><<<dim3(Mc / 128, Dc / 64, 1), bb, 0, stream>>>(
        ctx, ctx, ctx, wob, wob, wob, bo, bo, bo, out, out, out,
        1.0f, 1.0f, 1.0f, 0, 0, 0);
}

// Round 7
// 364.893 us; speedup vs baseline: 1.3839x; 1.1785x over previous
//
#include <hip/hip_runtime.h>
#include <math.h>

// Problem constants
constexpr int Bc  = 4;
constexpr int Sc  = 2048;
constexpr int Dc  = 512;
constexpr int Hc  = 8;
constexpr int DKc = 64;
constexpr int Mc  = Bc * Sc;   // 8192 rows

constexpr float SCALE_Q = 0.180336880111120426f;   // (1/8) * log2(e): /H quirk + exp2 base

typedef __attribute__((ext_vector_type(8)))  short s16x8;   // 8 bf16 MFMA frag
typedef __attribute__((ext_vector_type(4)))  float f32x4;   // 16x16 accumulator
typedef __attribute__((ext_vector_type(16))) float f32x16;  // 32x32 accumulator

__device__ __forceinline__ unsigned short f2bf(float f) {
    __bf16 h = (__bf16)f;                 // RNE convert
    return __builtin_bit_cast(unsigned short, h);
}

__device__ __forceinline__ float fexp2(float x) {
#if __has_builtin(__builtin_amdgcn_exp2f)
    return __builtin_amdgcn_exp2f(x);
#else
    return __expf(x * 0.6931471805599453f);
#endif
}

__device__ __forceinline__ uint4 pack8(float4 a, float4 b) {
    uint4 u;
    u.x = (unsigned)f2bf(a.x) | ((unsigned)f2bf(a.y) << 16);
    u.y = (unsigned)f2bf(a.z) | ((unsigned)f2bf(a.w) << 16);
    u.z = (unsigned)f2bf(b.x) | ((unsigned)f2bf(b.y) << 16);
    u.w = (unsigned)f2bf(b.z) | ((unsigned)f2bf(b.w) << 16);
    return u;
}

// ---------------------------------------------------------------------------
// mask [B,1,S,S] int32 -> keep-bit words: bit j of word w == (mask[w*64+j]!=0)
// 4-deep load batching (r6 version had 128 serial HBM rounds per wave);
// 16384 blocks -> every wave does exactly one batch of 4 words.
// ---------------------------------------------------------------------------
__global__ __launch_bounds__(256)
void pack_mask(const int* __restrict__ mask, unsigned long long* __restrict__ out,
               int nwords)
{
    int gw   = (blockIdx.x * blockDim.x + threadIdx.x) >> 6;
    int lane = threadIdx.x & 63;
    int nw   = (gridDim.x * blockDim.x) >> 6;
    for (int w0 = gw * 4; w0 < nwords; w0 += nw * 4) {
        int vals[4];
#pragma unroll
        for (int c = 0; c < 4; ++c)
            vals[c] = mask[(size_t)(w0 + c) * 64 + lane];   // independent coalesced loads
#pragma unroll
        for (int c = 0; c < 4; ++c) {
            unsigned long long bits = __ballot(vals[c] != 0);
            if (lane == 0) out[w0 + c] = bits;
        }
    }
}

// ---------------------------------------------------------------------------
// fp32 -> bf16 elementwise, 4 tensors (blockIdx.y selects), n4 float4s each
// ---------------------------------------------------------------------------
__global__ __launch_bounds__(256)
void cvt4(const float* __restrict__ i0, const float* __restrict__ i1,
          const float* __restrict__ i2, const float* __restrict__ i3,
          unsigned short* __restrict__ o0, unsigned short* __restrict__ o1,
          unsigned short* __restrict__ o2, unsigned short* __restrict__ o3,
          int n4)
{
    const float* in; unsigned short* out;
    switch (blockIdx.y) {
        case 0: in = i0; out = o0; break;
        case 1: in = i1; out = o1; break;
        case 2: in = i2; out = o2; break;
        default: in = i3; out = o3; break;
    }
    int i = blockIdx.x * 256 + threadIdx.x;
    if (i < n4) {
        float4 v = ((const float4*)in)[i];
        ushort4 r;
        r.x = f2bf(v.x); r.y = f2bf(v.y); r.z = f2bf(v.z); r.w = f2bf(v.w);
        ((ushort4*)out)[i] = r;
    }
}

// ---------------------------------------------------------------------------
// 128x64-tile bf16-MFMA GEMM: out = (X[M,512] @ W[512,512]^T + bias)*scale.
// blockIdx.z selects among up to 3 independent problems.
// XOR-swizzled unpadded LDS rows; double-buffered, one barrier per k-iter.
// LDS 48 KB -> LLVM targets 3 blocks/CU -> reg budget ~170 vs demand ~124:
// no spill (the budget is derived from LDS occupancy, NOT launch bounds —
// the r2..r6 counter series fits this model exactly).
// mode 0: fp32 flat [M,512]
// mode 1: bf16 head layout   [((b*H+h)*S+s)*64 + dk]
// mode 2: bf16 head transposed [((b*H+h)*64+dk)*S + swap23(s)]
// ---------------------------------------------------------------------------
template<bool XBF>
__global__ __launch_bounds__(256, 3)
void gemm128(const void* __restrict__ x0, const void* __restrict__ x1,
             const void* __restrict__ x2,
             const unsigned short* __restrict__ w0, const unsigned short* __restrict__ w1,
             const unsigned short* __restrict__ w2,
             const float* __restrict__ b0, const float* __restrict__ b1,
             const float* __restrict__ b2,
             void* __restrict__ o0v, void* __restrict__ o1v, void* __restrict__ o2v,
             float s0, float s1, float s2, int m0, int m1, int m2)
{
    const void* Xv; const unsigned short* W; const float* bias; void* outv;
    float scale; int mode;
    switch (blockIdx.z) {
        case 0:  Xv = x0; W = w0; bias = b0; outv = o0v; scale = s0; mode = m0; break;
        case 1:  Xv = x1; W = w1; bias = b1; outv = o1v; scale = s1; mode = m1; break;
        default: Xv = x2; W = w2; bias = b2; outv = o2v; scale = s2; mode = m2; break;
    }

    __shared__ unsigned short Xs[2][128 * 64];
    __shared__ unsigned short Ws[2][64 * 64];

    const int tid = threadIdx.x;
    const int w = tid >> 6, lane = tid & 63, ln = lane & 15, qd = lane >> 4;
    const int wm = (w >> 1) * 64, wn = (w & 1) * 32;
    const int row0 = blockIdx.x * 128, col0 = blockIdx.y * 64;

    f32x4 acc[4][2];
#pragma unroll
    for (int mt = 0; mt < 4; ++mt)
#pragma unroll
        for (int nt = 0; nt < 2; ++nt) acc[mt][nt] = f32x4{0.f, 0.f, 0.f, 0.f};

    uint4 xb[4], wr[2];
    auto load = [&](int k0) {
#pragma unroll
        for (int c = 0; c < 4; ++c) {
            int u = tid + c * 256, r = u >> 3, c8 = u & 7;
            if (XBF) {
                xb[c] = *(const uint4*)((const unsigned short*)Xv +
                                        (size_t)(row0 + r) * 512 + k0 + c8 * 8);
            } else {
                const float* xp = (const float*)Xv + (size_t)(row0 + r) * 512 + k0 + c8 * 8;
                xb[c] = pack8(*(const float4*)xp, *(const float4*)(xp + 4));
            }
        }
#pragma unroll
        for (int c = 0; c < 2; ++c) {
            int u = tid + c * 256, r = u >> 3, c8 = u & 7;
            wr[c] = *(const uint4*)(W + (size_t)(col0 + r) * 512 + k0 + c8 * 8);
        }
    };
    auto store = [&](int buf) {
#pragma unroll
        for (int c = 0; c < 4; ++c) {
            int u = tid + c * 256, r = u >> 3, c8 = u & 7;
            *(uint4*)&Xs[buf][r * 64 + ((c8 ^ (r & 7)) * 8)] = xb[c];
        }
#pragma unroll
        for (int c = 0; c < 2; ++c) {
            int u = tid + c * 256, r = u >> 3, c8 = u & 7;
            *(uint4*)&Ws[buf][r * 64 + ((c8 ^ (r & 7)) * 8)] = wr[c];
        }
    };

    load(0);
    store(0);
    for (int k0 = 0; k0 < 512; k0 += 64) {
        const int buf = (k0 >> 6) & 1;
        __syncthreads();
        if (k0 + 64 < 512) load(k0 + 64);   // overlaps compute below
#pragma unroll
        for (int kc = 0; kc < 2; ++kc) {
            s16x8 af[4], bfr[2];
#pragma unroll
            for (int mt = 0; mt < 4; ++mt) {
                int r = wm + mt * 16 + ln;   // r&7 == ln&7
                af[mt] = *(const s16x8*)&Xs[buf][r * 64 + (((kc * 4 + qd) ^ (ln & 7)) * 8)];
            }
#pragma unroll
            for (int nt = 0; nt < 2; ++nt) {
                int r = wn + nt * 16 + ln;
                bfr[nt] = *(const s16x8*)&Ws[buf][r * 64 + (((kc * 4 + qd) ^ (ln & 7)) * 8)];
            }
#pragma unroll
            for (int mt = 0; mt < 4; ++mt)
#pragma unroll
                for (int nt = 0; nt < 2; ++nt)
                    acc[mt][nt] = __builtin_amdgcn_mfma_f32_16x16x32_bf16(
                        af[mt], bfr[nt], acc[mt][nt], 0, 0, 0);
        }
        if (k0 + 64 < 512) store(buf ^ 1);
    }

    // epilogue: m = mbase + r (reg), n = col0+wn+nt*16+ln
#pragma unroll
    for (int nt = 0; nt < 2; ++nt) {
        const int n = col0 + wn + nt * 16 + ln;
        const float bz = bias[n];
#pragma unroll
        for (int mt = 0; mt < 4; ++mt) {
            const int mbase = row0 + wm + mt * 16 + qd * 4;
            if (mode == 0) {
                float* o = (float*)outv;
#pragma unroll
                for (int r = 0; r < 4; ++r)
                    o[(size_t)(mbase + r) * 512 + n] = acc[mt][nt][r] + bz;
            } else if (mode == 1) {
                unsigned short* o = (unsigned short*)outv;
                const int h = n >> 6, dk = n & 63;
#pragma unroll
                for (int r = 0; r < 4; ++r) {
                    int m = mbase + r, b = m >> 11, s = m & 2047;
                    o[((size_t)(b * Hc + h) * Sc + s) * 64 + dk] =
                        f2bf((acc[mt][nt][r] + bz) * scale);
                }
            } else {
                unsigned short* o = (unsigned short*)outv;
                const int h = n >> 6, dk = n & 63;
                const int b = mbase >> 11, sb = mbase & 2047;
                const int ss = (sb & ~12) | ((sb & 4) << 1) | ((sb & 8) >> 1); // swap bits 2,3
                ushort4 pk;
                pk.x = f2bf((acc[mt][nt][0] + bz) * scale);
                pk.y = f2bf((acc[mt][nt][1] + bz) * scale);
                pk.z = f2bf((acc[mt][nt][2] + bz) * scale);
                pk.w = f2bf((acc[mt][nt][3] + bz) * scale);
                *(ushort4*)(o + ((size_t)(b * Hc + h) * 64 + dk) * Sc + ss) = pk;
            }
        }
    }
}

// ---------------------------------------------------------------------------
// Split-K bf16 32x32x16-MFMA flash attention, max-free softmax.
// Grid (S/64, B*H), 256 thr = 4 waves = 2 q-groups x 2 key-halves.
// Math proven (r4-r6): p = exp2(masked s'), masked -> 0; PV B-frags are the
// lane's own p registers (V key axis swap23-permuted at projection); linear
// cross-half combine. Double-buffered LDS, one barrier/iter.
//
// KEY FIX (r6 post-mortem): LLVM sets the register budget from LDS-derived
// occupancy, ignoring the launch-bounds *minimum*. At 38 KB LDS it targeted
// 4 blocks/CU -> 128-reg budget -> ~150-reg demand spilled 250-500 MB to
// scratch every round (r2/r4/r5/r6 counters). Padding LDS to 56 KB forces
// 2 blocks/CU -> 256-reg budget -> no spill. Occupancy 8 waves/CU is enough:
// the spill round-trips were the dominant cost, not latency hiding.
// ---------------------------------------------------------------------------
__global__ __launch_bounds__(256, 2)
void attn_mfma(const unsigned short* __restrict__ qh, const unsigned short* __restrict__ kh,
               const unsigned short* __restrict__ vt, const unsigned* __restrict__ mbits,
               unsigned short* __restrict__ ctx)
{
    // 2 bufs x 28672 B regions (only 19456 used per buf) = 57344 B total:
    // deliberately oversized to pin occupancy at 2 blocks/CU (see header).
    __shared__ uint4 smem4[2][1792];

    const int bh = blockIdx.y, b = bh >> 3, h = bh & 7;
    const int q0 = blockIdx.x * 64;
    const int tid = threadIdx.x;
    const int w = tid >> 6;
    const int g = w >> 1;            // q-group
    const int kh_ = w & 1;           // key half
    const int lane = tid & 63, ln = lane & 31, hf = lane >> 5;
    const int qrow = q0 + g * 32 + ln;

    const int st = ((tid >> 7) << 6) | (tid & 63);   // staging id within kh-group

    // Q B-frags, resident
    s16x8 qf[4];
    {
        const unsigned short* qp = qh + ((size_t)bh * Sc + qrow) * 64 + hf * 8;
#pragma unroll
        for (int kc = 0; kc < 4; ++kc) qf[kc] = *(const s16x8*)(qp + kc * 16);
    }

    f32x16 o0, o1;
#pragma unroll
    for (int r = 0; r < 16; ++r) { o0[r] = 0.f; o1[r] = 0.f; }
    float lrun = 0.f;

    const unsigned* mrow = mbits + ((size_t)b * Sc + qrow) * (Sc / 32);
    const unsigned short* kbase = kh + (size_t)bh * Sc * 64;
    const unsigned short* vbase = vt + (size_t)bh * 64 * Sc;

    const int kt0 = kh_ * 1024;
    uint4 pre[4];
    auto load_tile = [&](int kt) {
#pragma unroll
        for (int c = 0; c < 2; ++c) {       // K: 32 rows x 8 chunks
            int idx = st + c * 128, r = idx >> 3, cc = idx & 7;
            pre[c] = *(const uint4*)(kbase + (size_t)(kt + r) * 64 + cc * 8);
        }
#pragma unroll
        for (int c = 2; c < 4; ++c) {       // V: 64 dv x 4 chunks (32 keys)
            int j = st + c * 128 - 256, dv = j >> 2, cc = j & 3;
            pre[c] = *(const uint4*)(vbase + (size_t)dv * Sc + kt + cc * 8);
        }
    };
    auto store_tile = [&](int buf) {
        unsigned short* Ks = (unsigned short*)((char*)smem4[buf] + kh_ * 9728);
        unsigned short* Vs = Ks + 4608 / 2;
#pragma unroll
        for (int c = 0; c < 2; ++c) {
            int idx = st + c * 128, r = idx >> 3, cc = idx & 7;
            *(uint4*)&Ks[r * 72 + cc * 8] = pre[c];
        }
#pragma unroll
        for (int c = 2; c < 4; ++c) {
            int j = st + c * 128 - 256, dv = j >> 2, cc = j & 3;
            *(uint4*)&Vs[dv * 40 + cc * 8] = pre[c];
        }
    };

    load_tile(kt0);
    unsigned mwn = mrow[kt0 >> 5];
    store_tile(0);

    for (int i = 0; i < 32; ++i) {
        const int kt = kt0 + i * 32;
        const int buf = i & 1;
        __syncthreads();
        const unsigned mw = mwn;
        if (i < 31) { load_tile(kt + 32); mwn = mrow[(kt + 32) >> 5]; }

        const unsigned short* Ks = (const unsigned short*)((char*)smem4[buf] + kh_ * 9728);
        const unsigned short* Vs = Ks + 4608 / 2;

        // ---- S^T[key][q] = K · Q^T  (32 keys)
        f32x16 sv;
#pragma unroll
        for (int r = 0; r < 16; ++r) sv[r] = 0.f;
#pragma unroll
        for (int kc = 0; kc < 4; ++kc) {
            s16x8 kf = *(const s16x8*)&Ks[ln * 72 + kc * 16 + hf * 8];
            sv = __builtin_amdgcn_mfma_f32_32x32x16_bf16(kf, qf[kc], sv, 0, 0, 0);
        }

        // ---- mask + exp2 (no max: scores bounded), pack to bf16 pairs
        float ps = 0.f;
        unsigned pu[8];
#pragma unroll
        for (int r = 0; r < 16; r += 2) {
            int key0 = (r & 3) + 8 * (r >> 2) + 4 * hf;
            int key1 = ((r + 1) & 3) + 8 * ((r + 1) >> 2) + 4 * hf;
            float a = ((mw >> key0) & 1u) ? sv[r]     : -1e9f;
            float c = ((mw >> key1) & 1u) ? sv[r + 1] : -1e9f;
            float p0 = fexp2(a), p1 = fexp2(c);
            ps += p0 + p1;
            pu[r >> 1] = (unsigned)f2bf(p0) | ((unsigned)f2bf(p1) << 16);
        }
        lrun += ps;

        // ---- ctx^T[dv][q] += V · P^T  (B-frags are own regs, kappa-order)
#pragma unroll
        for (int kc = 0; kc < 2; ++kc) {
            uint4 uu; uu.x = pu[4*kc]; uu.y = pu[4*kc+1]; uu.z = pu[4*kc+2]; uu.w = pu[4*kc+3];
            s16x8 pf  = __builtin_bit_cast(s16x8, uu);
            s16x8 v0  = *(const s16x8*)&Vs[ln * 40 + kc * 16 + hf * 8];
            s16x8 v1  = *(const s16x8*)&Vs[(32 + ln) * 40 + kc * 16 + hf * 8];
            o0 = __builtin_amdgcn_mfma_f32_32x32x16_bf16(v0, pf, o0, 0, 0, 0);
            o1 = __builtin_amdgcn_mfma_f32_32x32x16_bf16(v1, pf, o1, 0, 0, 0);
        }

        if (i < 31) store_tile(buf ^ 1);
    }

    // l is per-hf partial (each lane saw 16 of 32 keys per tile)
    lrun += __shfl_xor(lrun, 32);

    // ---- cross-kh combine (linear: no max state). kh=1 -> LDS, kh=0 adds.
    __syncthreads();
    float* cs = (float*)smem4[0];                    // [2][64][36] floats, 18432 B
    float* my = cs + ((size_t)(g * 64 + lane)) * 36;
    if (kh_ == 1) {
#pragma unroll
        for (int r = 0; r < 4; ++r) {
            float4 a; a.x = o0[4*r]; a.y = o0[4*r+1]; a.z = o0[4*r+2]; a.w = o0[4*r+3];
            float4 c; c.x = o1[4*r]; c.y = o1[4*r+1]; c.z = o1[4*r+2]; c.w = o1[4*r+3];
            *(float4*)(my + 4 * r)      = a;
            *(float4*)(my + 16 + 4 * r) = c;
        }
        my[32] = lrun;
    }
    __syncthreads();
    if (kh_ == 0) {
        lrun += my[32];
        const float inv = 1.f / lrun;
#pragma unroll
        for (int r = 0; r < 4; ++r) {
            float4 a = *(const float4*)(my + 4 * r);
            float4 c = *(const float4*)(my + 16 + 4 * r);
            o0[4*r]   = (o0[4*r]   + a.x) * inv; o0[4*r+1] = (o0[4*r+1] + a.y) * inv;
            o0[4*r+2] = (o0[4*r+2] + a.z) * inv; o0[4*r+3] = (o0[4*r+3] + a.w) * inv;
            o1[4*r]   = (o1[4*r]   + c.x) * inv; o1[4*r+1] = (o1[4*r+1] + c.y) * inv;
            o1[4*r+2] = (o1[4*r+2] + c.z) * inv; o1[4*r+3] = (o1[4*r+3] + c.w) * inv;
        }
        // ctx bf16 [B,S,D]; dv = 8g' + 4hf + t (+32 for o1)
        unsigned short* op = ctx + ((size_t)(b * Sc + qrow)) * 512 + h * 64;
#pragma unroll
        for (int gg = 0; gg < 4; ++gg) {
            ushort4 a, c;
            a.x = f2bf(o0[gg*4+0]); a.y = f2bf(o0[gg*4+1]);
            a.z = f2bf(o0[gg*4+2]); a.w = f2bf(o0[gg*4+3]);
            c.x = f2bf(o1[gg*4+0]); c.y = f2bf(o1[gg*4+1]);
            c.z = f2bf(o1[gg*4+2]); c.w = f2bf(o1[gg*4+3]);
            *(ushort4*)(op + 8 * gg + 4 * hf)      = a;
            *(ushort4*)(op + 32 + 8 * gg + 4 * hf) = c;
        }
    }
}

// ---------------------------------------------------------------------------
extern "C" void kernel_launch(void* const* d_in, const int* in_sizes, int n_in,
                              void* d_out, int out_size, void* d_ws, size_t ws_size,
                              hipStream_t stream)
{
    (void)in_sizes; (void)n_in; (void)out_size; (void)ws_size;

    const float* q    = (const float*)d_in[0];
    const float* k    = (const float*)d_in[1];
    const float* v    = (const float*)d_in[2];
    const int*   mask = (const int*)  d_in[3];
    const float* Wq   = (const float*)d_in[4];
    const float* bq   = (const float*)d_in[5];
    const float* Wk   = (const float*)d_in[6];
    const float* bk   = (const float*)d_in[7];
    const float* Wv   = (const float*)d_in[8];
    const float* bv   = (const float*)d_in[9];
    const float* Wo   = (const float*)d_in[10];
    const float* bo   = (const float*)d_in[11];
    float* out = (float*)d_out;

    // workspace carve; TEN = 4,194,304 elems
    constexpr size_t TEN = (size_t)Bc * Hc * Sc * DKc;
    char* p = (char*)d_ws;
    unsigned short* wqb   = (unsigned short*)p;  p += (size_t)Dc * Dc * 2;  // 0.5 MB
    unsigned short* wkb   = (unsigned short*)p;  p += (size_t)Dc * Dc * 2;
    unsigned short* wvb   = (unsigned short*)p;  p += (size_t)Dc * Dc * 2;
    unsigned short* wob   = (unsigned short*)p;  p += (size_t)Dc * Dc * 2;
    unsigned short* qh_bf = (unsigned short*)p;  p += TEN * 2;              // 8 MB
    unsigned short* kh_bf = (unsigned short*)p;  p += TEN * 2;
    unsigned short* vt_bf = (unsigned short*)p;  p += TEN * 2;
    unsigned short* ctx   = (unsigned short*)p;  p += TEN * 2;
    unsigned long long* mb64 = (unsigned long long*)p;                      // 2 MB

    const int nwords = Bc * Sc * (Sc / 64);   // 262144

    dim3 bb(256);

    pack_mask<<<dim3(16384), bb, 0, stream>>>(mask, mb64, nwords);
    cvt4<<<dim3(Dc * Dc / 4 / 256, 4), bb, 0, stream>>>(Wq, Wk, Wv, Wo, wqb, wkb, wvb, wob,
                                                        Dc * Dc / 4);
    // merged Q/K/V projections: one dispatch, 1536 blocks, 3 blocks/CU
    gemm128<false><<<dim3(Mc / 128, Dc / 64, 3), bb, 0, stream>>>(
        q, k, v, wqb, wkb, wvb, bq, bk, bv, qh_bf, kh_bf, vt_bf,
        SCALE_Q, 1.0f, 1.0f, 1, 1, 2);
    attn_mfma<<<dim3(Sc / 64, Bc * Hc), bb, 0, stream>>>(qh_bf, kh_bf, vt_bf,
                                                         (const unsigned*)mb64, ctx);
    gemm128<true><<<dim3(Mc / 128, Dc / 64, 1), bb, 0, stream>>>(
        ctx, ctx, ctx, wob, wob, wob, bo, bo, bo, out, out, out,
        1.0f, 1.0f, 1.0f, 0, 0, 0);
}

// Round 8
// 357.979 us; speedup vs baseline: 1.4106x; 1.0193x over previous
//
#include <hip/hip_runtime.h>
#include <math.h>

// Problem constants
constexpr int Bc  = 4;
constexpr int Sc  = 2048;
constexpr int Dc  = 512;
constexpr int Hc  = 8;
constexpr int DKc = 64;
constexpr int Mc  = Bc * Sc;   // 8192 rows

constexpr float SCALE_Q = 0.180336880111120426f;   // (1/8) * log2(e): /H quirk + exp2 base

typedef __attribute__((ext_vector_type(8)))  short s16x8;   // 8 bf16 MFMA frag
typedef __attribute__((ext_vector_type(4)))  float f32x4;   // 16x16 accumulator
typedef __attribute__((ext_vector_type(16))) float f32x16;  // 32x32 accumulator

__device__ __forceinline__ unsigned short f2bf(float f) {
    __bf16 h = (__bf16)f;                 // RNE convert
    return __builtin_bit_cast(unsigned short, h);
}

__device__ __forceinline__ float fexp2(float x) {
#if __has_builtin(__builtin_amdgcn_exp2f)
    return __builtin_amdgcn_exp2f(x);
#else
    return __expf(x * 0.6931471805599453f);
#endif
}

__device__ __forceinline__ uint4 pack8(float4 a, float4 b) {
    uint4 u;
    u.x = (unsigned)f2bf(a.x) | ((unsigned)f2bf(a.y) << 16);
    u.y = (unsigned)f2bf(a.z) | ((unsigned)f2bf(a.w) << 16);
    u.z = (unsigned)f2bf(b.x) | ((unsigned)f2bf(b.y) << 16);
    u.w = (unsigned)f2bf(b.z) | ((unsigned)f2bf(b.w) << 16);
    return u;
}

// ---------------------------------------------------------------------------
// mask [B,1,S,S] int32 -> keep-bit words: bit j of word w == (mask[w*64+j]!=0)
// ---------------------------------------------------------------------------
__global__ __launch_bounds__(256)
void pack_mask(const int* __restrict__ mask, unsigned long long* __restrict__ out,
               int nwords)
{
    int gw   = (blockIdx.x * blockDim.x + threadIdx.x) >> 6;
    int lane = threadIdx.x & 63;
    int nw   = (gridDim.x * blockDim.x) >> 6;
    for (int w0 = gw * 4; w0 < nwords; w0 += nw * 4) {
        int vals[4];
#pragma unroll
        for (int c = 0; c < 4; ++c)
            vals[c] = mask[(size_t)(w0 + c) * 64 + lane];
#pragma unroll
        for (int c = 0; c < 4; ++c) {
            unsigned long long bits = __ballot(vals[c] != 0);
            if (lane == 0) out[w0 + c] = bits;
        }
    }
}

// ---------------------------------------------------------------------------
// fp32 -> bf16 elementwise, 4 tensors (blockIdx.y selects), n4 float4s each
// ---------------------------------------------------------------------------
__global__ __launch_bounds__(256)
void cvt4(const float* __restrict__ i0, const float* __restrict__ i1,
          const float* __restrict__ i2, const float* __restrict__ i3,
          unsigned short* __restrict__ o0, unsigned short* __restrict__ o1,
          unsigned short* __restrict__ o2, unsigned short* __restrict__ o3,
          int n4)
{
    const float* in; unsigned short* out;
    switch (blockIdx.y) {
        case 0: in = i0; out = o0; break;
        case 1: in = i1; out = o1; break;
        case 2: in = i2; out = o2; break;
        default: in = i3; out = o3; break;
    }
    int i = blockIdx.x * 256 + threadIdx.x;
    if (i < n4) {
        float4 v = ((const float4*)in)[i];
        ushort4 r;
        r.x = f2bf(v.x); r.y = f2bf(v.y); r.z = f2bf(v.z); r.w = f2bf(v.w);
        ((ushort4*)out)[i] = r;
    }
}

// ---------------------------------------------------------------------------
// 128x64-tile bf16-MFMA GEMM (unchanged from r7 — no counters yet; attn first)
// ---------------------------------------------------------------------------
template<bool XBF>
__global__ __launch_bounds__(256, 3)
void gemm128(const void* __restrict__ x0, const void* __restrict__ x1,
             const void* __restrict__ x2,
             const unsigned short* __restrict__ w0, const unsigned short* __restrict__ w1,
             const unsigned short* __restrict__ w2,
             const float* __restrict__ b0, const float* __restrict__ b1,
             const float* __restrict__ b2,
             void* __restrict__ o0v, void* __restrict__ o1v, void* __restrict__ o2v,
             float s0, float s1, float s2, int m0, int m1, int m2)
{
    const void* Xv; const unsigned short* W; const float* bias; void* outv;
    float scale; int mode;
    switch (blockIdx.z) {
        case 0:  Xv = x0; W = w0; bias = b0; outv = o0v; scale = s0; mode = m0; break;
        case 1:  Xv = x1; W = w1; bias = b1; outv = o1v; scale = s1; mode = m1; break;
        default: Xv = x2; W = w2; bias = b2; outv = o2v; scale = s2; mode = m2; break;
    }

    __shared__ unsigned short Xs[2][128 * 64];
    __shared__ unsigned short Ws[2][64 * 64];

    const int tid = threadIdx.x;
    const int w = tid >> 6, lane = tid & 63, ln = lane & 15, qd = lane >> 4;
    const int wm = (w >> 1) * 64, wn = (w & 1) * 32;
    const int row0 = blockIdx.x * 128, col0 = blockIdx.y * 64;

    f32x4 acc[4][2];
#pragma unroll
    for (int mt = 0; mt < 4; ++mt)
#pragma unroll
        for (int nt = 0; nt < 2; ++nt) acc[mt][nt] = f32x4{0.f, 0.f, 0.f, 0.f};

    uint4 xb[4], wr[2];
    auto load = [&](int k0) {
#pragma unroll
        for (int c = 0; c < 4; ++c) {
            int u = tid + c * 256, r = u >> 3, c8 = u & 7;
            if (XBF) {
                xb[c] = *(const uint4*)((const unsigned short*)Xv +
                                        (size_t)(row0 + r) * 512 + k0 + c8 * 8);
            } else {
                const float* xp = (const float*)Xv + (size_t)(row0 + r) * 512 + k0 + c8 * 8;
                xb[c] = pack8(*(const float4*)xp, *(const float4*)(xp + 4));
            }
        }
#pragma unroll
        for (int c = 0; c < 2; ++c) {
            int u = tid + c * 256, r = u >> 3, c8 = u & 7;
            wr[c] = *(const uint4*)(W + (size_t)(col0 + r) * 512 + k0 + c8 * 8);
        }
    };
    auto store = [&](int buf) {
#pragma unroll
        for (int c = 0; c < 4; ++c) {
            int u = tid + c * 256, r = u >> 3, c8 = u & 7;
            *(uint4*)&Xs[buf][r * 64 + ((c8 ^ (r & 7)) * 8)] = xb[c];
        }
#pragma unroll
        for (int c = 0; c < 2; ++c) {
            int u = tid + c * 256, r = u >> 3, c8 = u & 7;
            *(uint4*)&Ws[buf][r * 64 + ((c8 ^ (r & 7)) * 8)] = wr[c];
        }
    };

    load(0);
    store(0);
    for (int k0 = 0; k0 < 512; k0 += 64) {
        const int buf = (k0 >> 6) & 1;
        __syncthreads();
        if (k0 + 64 < 512) load(k0 + 64);
#pragma unroll
        for (int kc = 0; kc < 2; ++kc) {
            s16x8 af[4], bfr[2];
#pragma unroll
            for (int mt = 0; mt < 4; ++mt) {
                int r = wm + mt * 16 + ln;
                af[mt] = *(const s16x8*)&Xs[buf][r * 64 + (((kc * 4 + qd) ^ (ln & 7)) * 8)];
            }
#pragma unroll
            for (int nt = 0; nt < 2; ++nt) {
                int r = wn + nt * 16 + ln;
                bfr[nt] = *(const s16x8*)&Ws[buf][r * 64 + (((kc * 4 + qd) ^ (ln & 7)) * 8)];
            }
#pragma unroll
            for (int mt = 0; mt < 4; ++mt)
#pragma unroll
                for (int nt = 0; nt < 2; ++nt)
                    acc[mt][nt] = __builtin_amdgcn_mfma_f32_16x16x32_bf16(
                        af[mt], bfr[nt], acc[mt][nt], 0, 0, 0);
        }
        if (k0 + 64 < 512) store(buf ^ 1);
    }

#pragma unroll
    for (int nt = 0; nt < 2; ++nt) {
        const int n = col0 + wn + nt * 16 + ln;
        const float bz = bias[n];
#pragma unroll
        for (int mt = 0; mt < 4; ++mt) {
            const int mbase = row0 + wm + mt * 16 + qd * 4;
            if (mode == 0) {
                float* o = (float*)outv;
#pragma unroll
                for (int r = 0; r < 4; ++r)
                    o[(size_t)(mbase + r) * 512 + n] = acc[mt][nt][r] + bz;
            } else if (mode == 1) {
                unsigned short* o = (unsigned short*)outv;
                const int h = n >> 6, dk = n & 63;
#pragma unroll
                for (int r = 0; r < 4; ++r) {
                    int m = mbase + r, b = m >> 11, s = m & 2047;
                    o[((size_t)(b * Hc + h) * Sc + s) * 64 + dk] =
                        f2bf((acc[mt][nt][r] + bz) * scale);
                }
            } else {
                unsigned short* o = (unsigned short*)outv;
                const int h = n >> 6, dk = n & 63;
                const int b = mbase >> 11, sb = mbase & 2047;
                const int ss = (sb & ~12) | ((sb & 4) << 1) | ((sb & 8) >> 1); // swap bits 2,3
                ushort4 pk;
                pk.x = f2bf((acc[mt][nt][0] + bz) * scale);
                pk.y = f2bf((acc[mt][nt][1] + bz) * scale);
                pk.z = f2bf((acc[mt][nt][2] + bz) * scale);
                pk.w = f2bf((acc[mt][nt][3] + bz) * scale);
                *(ushort4*)(o + ((size_t)(b * Hc + h) * 64 + dk) * Sc + ss) = pk;
            }
        }
    }
}

// ---------------------------------------------------------------------------
// Split-K bf16 32x32x16-MFMA flash attention, max-free softmax, DUAL Q-TILE.
// Grid (S/128, B*H), 256 thr = 4 waves = 2 q-groups x 2 key-halves.
// Wave (g,kh): q rows qA = q0+g*64+ln and qB = qA+32; keys kh*1024..+1024
// in 32-key tiles. Per iter the wave runs TWO independent streams (A,B)
// sharing the K/V LDS frag reads: 8 QK MFMA + 32 exps + 8 PV MFMA — double
// the ILP per barrier vs r7 (which was latency-bound at every pipe <30%,
// T_iter ~4500cyc vs ~900 issue demand). Blocks halve -> half the barriers.
// Math proven r4-r7: p=exp2(masked s'), masked->0; PV B-frags are the lane's
// own p regs (V key axis swap23-permuted at projection); linear combine.
// LDS deliberately 57344B (reported 73728) -> 2 blocks/CU -> 256-reg budget;
// reg demand ~230 fits (r7 proved the LDS-occupancy->budget model; watch
// WRITE_SIZE == 8 MB to confirm no spill).
// ---------------------------------------------------------------------------
__global__ __launch_bounds__(256, 2)
void attn_mfma(const unsigned short* __restrict__ qh, const unsigned short* __restrict__ kh,
               const unsigned short* __restrict__ vt, const unsigned* __restrict__ mbits,
               unsigned short* __restrict__ ctx)
{
    __shared__ uint4 smem4[2][1792];   // 57344 B: pins 2 blocks/CU (see header)

    const int bh = blockIdx.y, b = bh >> 3, h = bh & 7;
    const int q0 = blockIdx.x * 128;
    const int tid = threadIdx.x;
    const int w = tid >> 6;
    const int g = w >> 1;            // q-group
    const int kh_ = w & 1;           // key half
    const int lane = tid & 63, ln = lane & 31, hf = lane >> 5;
    const int qrA = q0 + g * 64 + ln;
    const int qrB = qrA + 32;

    const int st = ((tid >> 7) << 6) | (tid & 63);   // staging id within kh-group

    // Q B-frags for both tiles, resident
    s16x8 qfA[4], qfB[4];
    {
        const unsigned short* qpA = qh + ((size_t)bh * Sc + qrA) * 64 + hf * 8;
        const unsigned short* qpB = qh + ((size_t)bh * Sc + qrB) * 64 + hf * 8;
#pragma unroll
        for (int kc = 0; kc < 4; ++kc) {
            qfA[kc] = *(const s16x8*)(qpA + kc * 16);
            qfB[kc] = *(const s16x8*)(qpB + kc * 16);
        }
    }

    f32x16 oA0, oA1, oB0, oB1;
#pragma unroll
    for (int r = 0; r < 16; ++r) { oA0[r] = 0.f; oA1[r] = 0.f; oB0[r] = 0.f; oB1[r] = 0.f; }
    float lrA = 0.f, lrB = 0.f;

    const unsigned* mrA = mbits + ((size_t)b * Sc + qrA) * (Sc / 32);
    const unsigned* mrB = mbits + ((size_t)b * Sc + qrB) * (Sc / 32);
    const unsigned short* kbase = kh + (size_t)bh * Sc * 64;
    const unsigned short* vbase = vt + (size_t)bh * 64 * Sc;

    const int kt0 = kh_ * 1024;
    uint4 pre[4];
    auto load_tile = [&](int kt) {
#pragma unroll
        for (int c = 0; c < 2; ++c) {       // K: 32 rows x 8 chunks
            int idx = st + c * 128, r = idx >> 3, cc = idx & 7;
            pre[c] = *(const uint4*)(kbase + (size_t)(kt + r) * 64 + cc * 8);
        }
#pragma unroll
        for (int c = 2; c < 4; ++c) {       // V: 64 dv x 4 chunks (32 keys)
            int j = st + c * 128 - 256, dv = j >> 2, cc = j & 3;
            pre[c] = *(const uint4*)(vbase + (size_t)dv * Sc + kt + cc * 8);
        }
    };
    auto store_tile = [&](int buf) {
        unsigned short* Ks = (unsigned short*)((char*)smem4[buf] + kh_ * 9728);
        unsigned short* Vs = Ks + 4608 / 2;
#pragma unroll
        for (int c = 0; c < 2; ++c) {
            int idx = st + c * 128, r = idx >> 3, cc = idx & 7;
            *(uint4*)&Ks[r * 72 + cc * 8] = pre[c];
        }
#pragma unroll
        for (int c = 2; c < 4; ++c) {
            int j = st + c * 128 - 256, dv = j >> 2, cc = j & 3;
            *(uint4*)&Vs[dv * 40 + cc * 8] = pre[c];
        }
    };

    load_tile(kt0);
    unsigned mwnA = mrA[kt0 >> 5], mwnB = mrB[kt0 >> 5];
    store_tile(0);

    for (int i = 0; i < 32; ++i) {
        const int kt = kt0 + i * 32;
        const int buf = i & 1;
        __syncthreads();
        const unsigned mwA = mwnA, mwB = mwnB;
        if (i < 31) {
            load_tile(kt + 32);
            mwnA = mrA[(kt + 32) >> 5];
            mwnB = mrB[(kt + 32) >> 5];
        }

        const unsigned short* Ks = (const unsigned short*)((char*)smem4[buf] + kh_ * 9728);
        const unsigned short* Vs = Ks + 4608 / 2;

        // ---- S^T[key][q] = K · Q^T, both q-tiles share kf reads
        f32x16 svA, svB;
#pragma unroll
        for (int r = 0; r < 16; ++r) { svA[r] = 0.f; svB[r] = 0.f; }
#pragma unroll
        for (int kc = 0; kc < 4; ++kc) {
            s16x8 kf = *(const s16x8*)&Ks[ln * 72 + kc * 16 + hf * 8];
            svA = __builtin_amdgcn_mfma_f32_32x32x16_bf16(kf, qfA[kc], svA, 0, 0, 0);
            svB = __builtin_amdgcn_mfma_f32_32x32x16_bf16(kf, qfB[kc], svB, 0, 0, 0);
        }

        // ---- mask + exp2 (no max: scores bounded), pack to bf16 pairs
        float psA = 0.f, psB = 0.f;
        unsigned puA[8], puB[8];
#pragma unroll
        for (int r = 0; r < 16; r += 2) {
            int key0 = (r & 3) + 8 * (r >> 2) + 4 * hf;
            int key1 = ((r + 1) & 3) + 8 * ((r + 1) >> 2) + 4 * hf;
            float a0 = ((mwA >> key0) & 1u) ? svA[r]     : -1e9f;
            float a1 = ((mwA >> key1) & 1u) ? svA[r + 1] : -1e9f;
            float b0 = ((mwB >> key0) & 1u) ? svB[r]     : -1e9f;
            float b1 = ((mwB >> key1) & 1u) ? svB[r + 1] : -1e9f;
            float pA0 = fexp2(a0), pA1 = fexp2(a1);
            float pB0 = fexp2(b0), pB1 = fexp2(b1);
            psA += pA0 + pA1;  psB += pB0 + pB1;
            puA[r >> 1] = (unsigned)f2bf(pA0) | ((unsigned)f2bf(pA1) << 16);
            puB[r >> 1] = (unsigned)f2bf(pB0) | ((unsigned)f2bf(pB1) << 16);
        }
        lrA += psA;  lrB += psB;

        // ---- ctx^T[dv][q] += V · P^T, both q-tiles share V reads
#pragma unroll
        for (int kc = 0; kc < 2; ++kc) {
            uint4 ua; ua.x = puA[4*kc]; ua.y = puA[4*kc+1]; ua.z = puA[4*kc+2]; ua.w = puA[4*kc+3];
            uint4 ub; ub.x = puB[4*kc]; ub.y = puB[4*kc+1]; ub.z = puB[4*kc+2]; ub.w = puB[4*kc+3];
            s16x8 pfA = __builtin_bit_cast(s16x8, ua);
            s16x8 pfB = __builtin_bit_cast(s16x8, ub);
            s16x8 v0  = *(const s16x8*)&Vs[ln * 40 + kc * 16 + hf * 8];
            s16x8 v1  = *(const s16x8*)&Vs[(32 + ln) * 40 + kc * 16 + hf * 8];
            oA0 = __builtin_amdgcn_mfma_f32_32x32x16_bf16(v0, pfA, oA0, 0, 0, 0);
            oB0 = __builtin_amdgcn_mfma_f32_32x32x16_bf16(v0, pfB, oB0, 0, 0, 0);
            oA1 = __builtin_amdgcn_mfma_f32_32x32x16_bf16(v1, pfA, oA1, 0, 0, 0);
            oB1 = __builtin_amdgcn_mfma_f32_32x32x16_bf16(v1, pfB, oB1, 0, 0, 0);
        }

        if (i < 31) store_tile(buf ^ 1);
    }

    // l per-hf partial -> full
    lrA += __shfl_xor(lrA, 32);
    lrB += __shfl_xor(lrB, 32);

    // ---- cross-kh combine (linear). kh=1 -> LDS, kh=0 adds + writes.
    __syncthreads();
    float* cs = (float*)smem4[0];                    // [2][64][66] floats = 33792 B
    float* my = cs + ((size_t)(g * 64 + lane)) * 66;
    if (kh_ == 1) {
#pragma unroll
        for (int r = 0; r < 4; ++r) {
            float4 a0; a0.x = oA0[4*r]; a0.y = oA0[4*r+1]; a0.z = oA0[4*r+2]; a0.w = oA0[4*r+3];
            float4 a1; a1.x = oA1[4*r]; a1.y = oA1[4*r+1]; a1.z = oA1[4*r+2]; a1.w = oA1[4*r+3];
            float4 b0; b0.x = oB0[4*r]; b0.y = oB0[4*r+1]; b0.z = oB0[4*r+2]; b0.w = oB0[4*r+3];
            float4 b1; b1.x = oB1[4*r]; b1.y = oB1[4*r+1]; b1.z = oB1[4*r+2]; b1.w = oB1[4*r+3];
            *(float4*)(my + 4 * r)      = a0;
            *(float4*)(my + 16 + 4 * r) = a1;
            *(float4*)(my + 32 + 4 * r) = b0;
            *(float4*)(my + 48 + 4 * r) = b1;
        }
        my[64] = lrA;
        my[65] = lrB;
    }
    __syncthreads();
    if (kh_ == 0) {
        lrA += my[64];
        lrB += my[65];
        const float invA = 1.f / lrA, invB = 1.f / lrB;
#pragma unroll
        for (int r = 0; r < 4; ++r) {
            float4 a0 = *(const float4*)(my + 4 * r);
            float4 a1 = *(const float4*)(my + 16 + 4 * r);
            float4 b0 = *(const float4*)(my + 32 + 4 * r);
            float4 b1 = *(const float4*)(my + 48 + 4 * r);
            oA0[4*r]   = (oA0[4*r]   + a0.x) * invA; oA0[4*r+1] = (oA0[4*r+1] + a0.y) * invA;
            oA0[4*r+2] = (oA0[4*r+2] + a0.z) * invA; oA0[4*r+3] = (oA0[4*r+3] + a0.w) * invA;
            oA1[4*r]   = (oA1[4*r]   + a1.x) * invA; oA1[4*r+1] = (oA1[4*r+1] + a1.y) * invA;
            oA1[4*r+2] = (oA1[4*r+2] + a1.z) * invA; oA1[4*r+3] = (oA1[4*r+3] + a1.w) * invA;
            oB0[4*r]   = (oB0[4*r]   + b0.x) * invB; oB0[4*r+1] = (oB0[4*r+1] + b0.y) * invB;
            oB0[4*r+2] = (oB0[4*r+2] + b0.z) * invB; oB0[4*r+3] = (oB0[4*r+3] + b0.w) * invB;
            oB1[4*r]   = (oB1[4*r]   + b1.x) * invB; oB1[4*r+1] = (oB1[4*r+1] + b1.y) * invB;
            oB1[4*r+2] = (oB1[4*r+2] + b1.z) * invB; oB1[4*r+3] = (oB1[4*r+3] + b1.w) * invB;
        }
        // ctx bf16 [B,S,D]; dv = 8*gg + 4*hf + t (+32 for the *1 half)
        unsigned short* opA = ctx + ((size_t)(b * Sc + qrA)) * 512 + h * 64;
        unsigned short* opB = ctx + ((size_t)(b * Sc + qrB)) * 512 + h * 64;
#pragma unroll
        for (int gg = 0; gg < 4; ++gg) {
            ushort4 a, c;
            a.x = f2bf(oA0[gg*4+0]); a.y = f2bf(oA0[gg*4+1]);
            a.z = f2bf(oA0[gg*4+2]); a.w = f2bf(oA0[gg*4+3]);
            c.x = f2bf(oA1[gg*4+0]); c.y = f2bf(oA1[gg*4+1]);
            c.z = f2bf(oA1[gg*4+2]); c.w = f2bf(oA1[gg*4+3]);
            *(ushort4*)(opA + 8 * gg + 4 * hf)      = a;
            *(ushort4*)(opA + 32 + 8 * gg + 4 * hf) = c;
            ushort4 d, e;
            d.x = f2bf(oB0[gg*4+0]); d.y = f2bf(oB0[gg*4+1]);
            d.z = f2bf(oB0[gg*4+2]); d.w = f2bf(oB0[gg*4+3]);
            e.x = f2bf(oB1[gg*4+0]); e.y = f2bf(oB1[gg*4+1]);
            e.z = f2bf(oB1[gg*4+2]); e.w = f2bf(oB1[gg*4+3]);
            *(ushort4*)(opB + 8 * gg + 4 * hf)      = d;
            *(ushort4*)(opB + 32 + 8 * gg + 4 * hf) = e;
        }
    }
}

// ---------------------------------------------------------------------------
extern "C" void kernel_launch(void* const* d_in, const int* in_sizes, int n_in,
                              void* d_out, int out_size, void* d_ws, size_t ws_size,
                              hipStream_t stream)
{
    (void)in_sizes; (void)n_in; (void)out_size; (void)ws_size;

    const float* q    = (const float*)d_in[0];
    const float* k    = (const float*)d_in[1];
    const float* v    = (const float*)d_in[2];
    const int*   mask = (const int*)  d_in[3];
    const float* Wq   = (const float*)d_in[4];
    const float* bq   = (const float*)d_in[5];
    const float* Wk   = (const float*)d_in[6];
    const float* bk   = (const float*)d_in[7];
    const float* Wv   = (const float*)d_in[8];
    const float* bv   = (const float*)d_in[9];
    const float* Wo   = (const float*)d_in[10];
    const float* bo   = (const float*)d_in[11];
    float* out = (float*)d_out;

    // workspace carve; TEN = 4,194,304 elems
    constexpr size_t TEN = (size_t)Bc * Hc * Sc * DKc;
    char* p = (char*)d_ws;
    unsigned short* wqb   = (unsigned short*)p;  p += (size_t)Dc * Dc * 2;  // 0.5 MB
    unsigned short* wkb   = (unsigned short*)p;  p += (size_t)Dc * Dc * 2;
    unsigned short* wvb   = (unsigned short*)p;  p += (size_t)Dc * Dc * 2;
    unsigned short* wob   = (unsigned short*)p;  p += (size_t)Dc * Dc * 2;
    unsigned short* qh_bf = (unsigned short*)p;  p += TEN * 2;              // 8 MB
    unsigned short* kh_bf = (unsigned short*)p;  p += TEN * 2;
    unsigned short* vt_bf = (unsigned short*)p;  p += TEN * 2;
    unsigned short* ctx   = (unsigned short*)p;  p += TEN * 2;
    unsigned long long* mb64 = (unsigned long long*)p;                      // 2 MB

    const int nwords = Bc * Sc * (Sc / 64);   // 262144

    dim3 bb(256);

    pack_mask<<<dim3(16384), bb, 0, stream>>>(mask, mb64, nwords);
    cvt4<<<dim3(Dc * Dc / 4 / 256, 4), bb, 0, stream>>>(Wq, Wk, Wv, Wo, wqb, wkb, wvb, wob,
                                                        Dc * Dc / 4);
    // merged Q/K/V projections: one dispatch, 1536 blocks, 3 blocks/CU
    gemm128<false><<<dim3(Mc / 128, Dc / 64, 3), bb, 0, stream>>>(
        q, k, v, wqb, wkb, wvb, bq, bk, bv, qh_bf, kh_bf, vt_bf,
        SCALE_Q, 1.0f, 1.0f, 1, 1, 2);
    attn_mfma<<<dim3(Sc / 128, Bc * Hc), bb, 0, stream>>>(qh_bf, kh_bf, vt_bf,
                                                          (const unsigned*)mb64, ctx);
    gemm128<true><<<dim3(Mc / 128, Dc / 64, 1), bb, 0, stream>>>(
        ctx, ctx, ctx, wob, wob, wob, bo, bo, bo, out, out, out,
        1.0f, 1.0f, 1.0f, 0, 0, 0);
}